// Round 1
// baseline (1561.626 us; speedup 1.0000x reference)
//
#include <hip/hip_runtime.h>
#include <math.h>

#define NN_ 40000
#define NE_ 640000
#define NG_ 400

// ---------------- device scratch (module-allocated; re-initialized every launch) ----
__device__ int   g_deg[NN_];
__device__ int   g_rowstart[NN_ + 1];
__device__ int   g_cursor[NN_];
__device__ int   g_edgepos[NE_];
__device__ int   g_srccsr[NE_];
__device__ float g_ecsr[(size_t)NE_ * 4];
__device__ float g_h1[(size_t)NN_ * 256];
__device__ float g_xl2[(size_t)NN_ * 256];
__device__ float g_xr2[(size_t)NN_ * 256];
__device__ float g_h2[(size_t)NN_ * 128];
__device__ float g_sum[256], g_sq[256];
__device__ float g_scale[256], g_shift[256];
__device__ float g_pool[NG_ * 128];
__device__ int   g_count[NG_];

// ---------------- init ----------------
__global__ void k_zero() {
    int i = blockIdx.x * blockDim.x + threadIdx.x;
    int stride = gridDim.x * blockDim.x;
    for (int j = i; j < NN_; j += stride) g_deg[j] = 0;
    for (int j = i; j < NG_ * 128; j += stride) g_pool[j] = 0.f;
    for (int j = i; j < NG_; j += stride) g_count[j] = 0;
    for (int j = i; j < 256; j += stride) { g_sum[j] = 0.f; g_sq[j] = 0.f; }
}

// ---------------- CSR build ----------------
__global__ void k_hist(const int* __restrict__ dst) {
    int e = blockIdx.x * blockDim.x + threadIdx.x;
    if (e < NE_) atomicAdd(&g_deg[dst[e]], 1);
}

__global__ void k_scan() {
    __shared__ int sd[1024];
    __shared__ int carry;
    int tid = threadIdx.x;
    if (tid == 0) carry = 0;
    __syncthreads();
    for (int base = 0; base < NN_; base += 1024) {
        int i = base + tid;
        int v = (i < NN_) ? g_deg[i] : 0;
        sd[tid] = v;
        __syncthreads();
        for (int off = 1; off < 1024; off <<= 1) {
            int t = (tid >= off) ? sd[tid - off] : 0;
            __syncthreads();
            sd[tid] += t;
            __syncthreads();
        }
        int excl = sd[tid] - v + carry;
        if (i < NN_) { g_rowstart[i] = excl; g_cursor[i] = excl; }
        int total = sd[1023];
        __syncthreads();
        if (tid == 0) carry += total;
        __syncthreads();
    }
    if (tid == 0) g_rowstart[NN_] = carry;
}

__global__ void k_scatter(const int* __restrict__ src, const int* __restrict__ dst) {
    int e = blockIdx.x * blockDim.x + threadIdx.x;
    if (e < NE_) {
        int pos = atomicAdd(&g_cursor[dst[e]], 1);
        g_edgepos[e] = pos;
        g_srccsr[pos] = src[e];
    }
}

// ---------------- layer 1: per-edge attention logits ----------------
// wave per edge; lane handles channels c = j*64 + lane (j == head for H=4,C=64)
__global__ void k_l1_logits(const float* __restrict__ x, const int* __restrict__ src,
                            const int* __restrict__ dst, const float* __restrict__ ea,
                            const float* __restrict__ Wl, const float* __restrict__ bl,
                            const float* __restrict__ Wr, const float* __restrict__ br,
                            const float* __restrict__ We, const float* __restrict__ att) {
    __shared__ float sWl0[256], sWl1[256], sWr0[256], sWr1[256], sbl[256], sbr[256];
    __shared__ float sWe[4][256], satt[256];
    int tid = threadIdx.x;
    sWl0[tid] = Wl[tid]; sWl1[tid] = Wl[256 + tid];
    sWr0[tid] = Wr[tid]; sWr1[tid] = Wr[256 + tid];
    sbl[tid] = bl[tid];  sbr[tid] = br[tid];
    sWe[0][tid] = We[tid]; sWe[1][tid] = We[256 + tid];
    sWe[2][tid] = We[512 + tid]; sWe[3][tid] = We[768 + tid];
    satt[tid] = att[tid];
    __syncthreads();
    int wv = tid >> 6, lane = tid & 63;
    int e = blockIdx.x * 4 + wv;
    if (e >= NE_) return;
    int s = src[e], d = dst[e];
    float xs0 = x[2 * s], xs1 = x[2 * s + 1];
    float xd0 = x[2 * d], xd1 = x[2 * d + 1];
    const float4 eav = *reinterpret_cast<const float4*>(ea + 4 * (size_t)e);
    float p[4];
#pragma unroll
    for (int j = 0; j < 4; ++j) {
        int c = j * 64 + lane;
        float z = xs0 * sWl0[c] + xs1 * sWl1[c] + sbl[c]
                + xd0 * sWr0[c] + xd1 * sWr1[c] + sbr[c]
                + eav.x * sWe[0][c] + eav.y * sWe[1][c]
                + eav.z * sWe[2][c] + eav.w * sWe[3][c];
        z = z > 0.f ? z : 0.2f * z;
        p[j] = z * satt[c];
    }
#pragma unroll
    for (int off = 1; off < 64; off <<= 1) {
#pragma unroll
        for (int j = 0; j < 4; ++j) p[j] += __shfl_xor(p[j], off);
    }
    if (lane == 0) {
        float4 v = make_float4(p[0], p[1], p[2], p[3]);
        *reinterpret_cast<float4*>(&g_ecsr[(size_t)g_edgepos[e] * 4]) = v;
    }
}

// ---------------- layer 1: per-node softmax + aggregate (xl recomputed from x) ----
__global__ void k_l1_agg(const float* __restrict__ x, const float* __restrict__ Wl,
                         const float* __restrict__ bl, const float* __restrict__ bias1) {
    int n = blockIdx.x;
    int c = threadIdx.x;          // 256; head = c>>6 (same for whole wave)
    int h = c >> 6;
    int s0 = g_rowstart[n], d = g_rowstart[n + 1] - s0;
    float wl0 = Wl[c], wl1 = Wl[256 + c], blc = bl[c];
    float m = -INFINITY;
    for (int i = 0; i < d; ++i) m = fmaxf(m, g_ecsr[(size_t)(s0 + i) * 4 + h]);
    float den = 0.f;
    for (int i = 0; i < d; ++i) den += expf(g_ecsr[(size_t)(s0 + i) * 4 + h] - m);
    float inv = 1.f / (den + 1e-16f);
    float acc = 0.f;
    for (int i = 0; i < d; ++i) {
        int s = g_srccsr[s0 + i];
        float w = expf(g_ecsr[(size_t)(s0 + i) * 4 + h] - m) * inv;
        float xlv = x[2 * s] * wl0 + x[2 * s + 1] * wl1 + blc;
        acc += w * xlv;
    }
    g_h1[(size_t)n * 256 + c] = acc + bias1[c];
}

// ---------------- batchnorm ----------------
template <int C>
__global__ void k_bn_stats() {
    const float* h = (C == 256) ? (const float*)g_h1 : (const float*)g_h2;
    int c = threadIdx.x;
    int r0 = blockIdx.x * 100;
    float s = 0.f, ss = 0.f;
    for (int r = 0; r < 100; ++r) {
        float v = h[(size_t)(r0 + r) * C + c];
        s += v; ss += v * v;
    }
    atomicAdd(&g_sum[c], s);
    atomicAdd(&g_sq[c], ss);
}

template <int C>
__global__ void k_bn_finalize(const float* __restrict__ g, const float* __restrict__ b) {
    int c = threadIdx.x;
    float mu = g_sum[c] / (float)NN_;
    float var = g_sq[c] / (float)NN_ - mu * mu;
    float sc = g[c] * rsqrtf(var + 1e-5f);
    g_scale[c] = sc;
    g_shift[c] = b[c] - mu * sc;
    g_sum[c] = 0.f; g_sq[c] = 0.f;  // ready for next BN
}

template <int C>
__global__ void k_bn_apply() {
    float* h = (C == 256) ? (float*)g_h1 : (float*)g_h2;
    int i = blockIdx.x * blockDim.x + threadIdx.x;
    int stride = gridDim.x * blockDim.x;
    for (int j = i; j < NN_ * C; j += stride) {
        int c = j & (C - 1);
        float v = h[j] * g_scale[c] + g_shift[c];
        h[j] = v > 0.f ? v : expm1f(v);
    }
}

// ---------------- SGEMM: (40000x256) @ (256x256) + bias -> g_xl2 / g_xr2 ----------
__global__ void k_gemm(const float* __restrict__ W, const float* __restrict__ bias, int sel) {
    const float* A = g_h1;
    float* C = sel ? g_xr2 : g_xl2;
    const int K = 256, NNc = 256;
    __shared__ float As[32][65];   // As[k][m] (transposed, +1 pad)
    __shared__ float Bs[32][64];   // Bs[k][n]
    int tid = threadIdx.x;
    int tx = tid & 15, ty = tid >> 4;
    int m0 = blockIdx.x * 64, n0 = blockIdx.y * 64;
    int la_r = tid >> 2;            // 0..63 row (m)
    int la_c = (tid & 3) * 8;       // k offset
    int lb_r = tid >> 3;            // 0..31 (k)
    int lb_c = (tid & 7) * 8;       // n offset
    float acc[4][4] = {};
    for (int k0 = 0; k0 < K; k0 += 32) {
        const float4* Ap = reinterpret_cast<const float4*>(A + (size_t)(m0 + la_r) * K + k0 + la_c);
        float4 a0 = Ap[0], a1 = Ap[1];
        As[la_c + 0][la_r] = a0.x; As[la_c + 1][la_r] = a0.y;
        As[la_c + 2][la_r] = a0.z; As[la_c + 3][la_r] = a0.w;
        As[la_c + 4][la_r] = a1.x; As[la_c + 5][la_r] = a1.y;
        As[la_c + 6][la_r] = a1.z; As[la_c + 7][la_r] = a1.w;
        const float4* Wp = reinterpret_cast<const float4*>(W + (size_t)(k0 + lb_r) * NNc + n0 + lb_c);
        *reinterpret_cast<float4*>(&Bs[lb_r][lb_c]) = Wp[0];
        *reinterpret_cast<float4*>(&Bs[lb_r][lb_c + 4]) = Wp[1];
        __syncthreads();
#pragma unroll
        for (int k = 0; k < 32; ++k) {
            float a[4], b[4];
#pragma unroll
            for (int i = 0; i < 4; ++i) a[i] = As[k][ty * 4 + i];
#pragma unroll
            for (int j = 0; j < 4; ++j) b[j] = Bs[k][tx * 4 + j];
#pragma unroll
            for (int i = 0; i < 4; ++i)
#pragma unroll
                for (int j = 0; j < 4; ++j) acc[i][j] += a[i] * b[j];
        }
        __syncthreads();
    }
#pragma unroll
    for (int i = 0; i < 4; ++i) {
        int m = m0 + ty * 4 + i;
#pragma unroll
        for (int j = 0; j < 4; ++j) {
            int n = n0 + tx * 4 + j;
            C[(size_t)m * NNc + n] = acc[i][j] + bias[n];
        }
    }
}

// ---------------- layer 2: per-edge attention logits ----------------
__global__ void k_l2_logits(const int* __restrict__ src, const int* __restrict__ dst,
                            const float* __restrict__ ea, const float* __restrict__ We,
                            const float* __restrict__ att) {
    __shared__ float sWe[4][256], satt[256];
    int tid = threadIdx.x;
    sWe[0][tid] = We[tid]; sWe[1][tid] = We[256 + tid];
    sWe[2][tid] = We[512 + tid]; sWe[3][tid] = We[768 + tid];
    satt[tid] = att[tid];
    __syncthreads();
    int wv = tid >> 6, lane = tid & 63;
    int e = blockIdx.x * 4 + wv;
    if (e >= NE_) return;
    int s = src[e], d = dst[e];
    const float4 eav = *reinterpret_cast<const float4*>(ea + 4 * (size_t)e);
    float p[4];
#pragma unroll
    for (int j = 0; j < 4; ++j) {
        int c = j * 64 + lane;
        float z = g_xl2[(size_t)s * 256 + c] + g_xr2[(size_t)d * 256 + c]
                + eav.x * sWe[0][c] + eav.y * sWe[1][c]
                + eav.z * sWe[2][c] + eav.w * sWe[3][c];
        z = z > 0.f ? z : 0.2f * z;
        p[j] = z * satt[c];
    }
    float p0 = p[0] + p[1], p1 = p[2] + p[3];  // head0 = c<128, head1 = c>=128
#pragma unroll
    for (int off = 1; off < 64; off <<= 1) {
        p0 += __shfl_xor(p0, off);
        p1 += __shfl_xor(p1, off);
    }
    if (lane == 0) {
        float2 v = make_float2(p0, p1);
        *reinterpret_cast<float2*>(&g_ecsr[(size_t)g_edgepos[e] * 2]) = v;
    }
}

// ---------------- layer 2: per-node softmax + aggregate + head-mean ----------------
__global__ void k_l2_agg(const float* __restrict__ bias2) {
    int n = blockIdx.x;
    int c = threadIdx.x;          // 256: head = c>>7
    int h = c >> 7;
    int s0 = g_rowstart[n], d = g_rowstart[n + 1] - s0;
    float m = -INFINITY;
    for (int i = 0; i < d; ++i) m = fmaxf(m, g_ecsr[(size_t)(s0 + i) * 2 + h]);
    float den = 0.f;
    for (int i = 0; i < d; ++i) den += expf(g_ecsr[(size_t)(s0 + i) * 2 + h] - m);
    float inv = 1.f / (den + 1e-16f);
    float acc = 0.f;
    for (int i = 0; i < d; ++i) {
        int s = g_srccsr[s0 + i];
        float w = expf(g_ecsr[(size_t)(s0 + i) * 2 + h] - m) * inv;
        acc += w * g_xl2[(size_t)s * 256 + c];
    }
    __shared__ float tmp[256];
    tmp[c] = acc;
    __syncthreads();
    if (c < 128) g_h2[(size_t)n * 128 + c] = 0.5f * (tmp[c] + tmp[c + 128]) + bias2[c];
}

// ---------------- global mean pool ----------------
__global__ void k_pool(const int* __restrict__ batch) {
    int i = blockIdx.x * blockDim.x + threadIdx.x;
    int stride = gridDim.x * blockDim.x;
    for (int j = i; j < NN_ * 128; j += stride) {
        int n = j >> 7, c = j & 127;
        int b = batch[n];
        atomicAdd(&g_pool[b * 128 + c], g_h2[j]);
        if (c == 0) atomicAdd(&g_count[b], 1);
    }
}

// ---------------- MLP head ----------------
__global__ void k_head(const float* __restrict__ W1, const float* __restrict__ b1,
                       const float* __restrict__ W2, const float* __restrict__ b2,
                       float* __restrict__ out) {
    int g = blockIdx.x, t = threadIdx.x;  // 64 threads
    __shared__ float p[128], hm[64];
    float cnt = fmaxf((float)g_count[g], 1.f);
    float inv = 1.f / cnt;
    p[t] = g_pool[g * 128 + t] * inv;
    p[t + 64] = g_pool[g * 128 + 64 + t] * inv;
    __syncthreads();
    float a = b1[t];
    for (int k = 0; k < 128; ++k) a += p[k] * W1[k * 64 + t];
    hm[t] = a > 0.f ? a : expm1f(a);
    __syncthreads();
    if (t < 12) {
        float o = b2[t];
        for (int k = 0; k < 64; ++k) o += hm[k] * W2[k * 12 + t];
        out[g * 12 + t] = o;
    }
}

// ---------------- launch ----------------
extern "C" void kernel_launch(void* const* d_in, const int* in_sizes, int n_in,
                              void* d_out, int out_size, void* d_ws, size_t ws_size,
                              hipStream_t stream) {
    const float* x     = (const float*)d_in[0];
    const int*   ei    = (const int*)d_in[1];
    const float* ea    = (const float*)d_in[2];
    const int*   batch = (const int*)d_in[3];
    const float* Wl1   = (const float*)d_in[4];
    const float* bl1   = (const float*)d_in[5];
    const float* Wr1   = (const float*)d_in[6];
    const float* br1   = (const float*)d_in[7];
    const float* We1   = (const float*)d_in[8];
    const float* att1  = (const float*)d_in[9];
    const float* bias1 = (const float*)d_in[10];
    const float* g1    = (const float*)d_in[11];
    const float* be1   = (const float*)d_in[12];
    const float* Wl2   = (const float*)d_in[13];
    const float* bl2   = (const float*)d_in[14];
    const float* Wr2   = (const float*)d_in[15];
    const float* br2   = (const float*)d_in[16];
    const float* We2   = (const float*)d_in[17];
    const float* att2  = (const float*)d_in[18];
    const float* bias2 = (const float*)d_in[19];
    const float* g2    = (const float*)d_in[20];
    const float* be2   = (const float*)d_in[21];
    const float* Wlin1 = (const float*)d_in[22];
    const float* blin1 = (const float*)d_in[23];
    const float* Wlin2 = (const float*)d_in[24];
    const float* blin2 = (const float*)d_in[25];
    float* out = (float*)d_out;
    const int* src = ei;
    const int* dst = ei + NE_;

    k_zero<<<256, 256, 0, stream>>>();
    k_hist<<<2500, 256, 0, stream>>>(dst);
    k_scan<<<1, 1024, 0, stream>>>();
    k_scatter<<<2500, 256, 0, stream>>>(src, dst);

    // layer 1
    k_l1_logits<<<160000, 256, 0, stream>>>(x, src, dst, ea, Wl1, bl1, Wr1, br1, We1, att1);
    k_l1_agg<<<40000, 256, 0, stream>>>(x, Wl1, bl1, bias1);
    k_bn_stats<256><<<400, 256, 0, stream>>>();
    k_bn_finalize<256><<<1, 256, 0, stream>>>(g1, be1);
    k_bn_apply<256><<<4096, 256, 0, stream>>>();

    // layer 2 projections
    k_gemm<<<dim3(625, 4), 256, 0, stream>>>(Wl2, bl2, 0);
    k_gemm<<<dim3(625, 4), 256, 0, stream>>>(Wr2, br2, 1);

    // layer 2
    k_l2_logits<<<160000, 256, 0, stream>>>(src, dst, ea, We2, att2);
    k_l2_agg<<<40000, 256, 0, stream>>>(bias2);
    k_bn_stats<128><<<400, 128, 0, stream>>>();
    k_bn_finalize<128><<<1, 128, 0, stream>>>(g2, be2);
    k_bn_apply<128><<<4096, 256, 0, stream>>>();

    // pool + head
    k_pool<<<2048, 256, 0, stream>>>(batch);
    k_head<<<NG_, 64, 0, stream>>>(Wlin1, blin1, Wlin2, blin2, out);
}

// Round 2
// 1039.462 us; speedup vs baseline: 1.5023x; 1.5023x over previous
//
#include <hip/hip_runtime.h>
#include <math.h>

#define NN_ 40000
#define NE_ 640000
#define NG_ 400
#define MAXD 256   // max in-degree supported by the LDS fast path (Poisson(16) max ~50)

// ---------------- device scratch (module-allocated; re-initialized every launch) ----
__device__ int   g_deg[NN_];
__device__ int   g_rowstart[NN_ + 1];
__device__ int   g_cursor[NN_];
__device__ int   g_edgepos[NE_];
__device__ int   g_srccsr[NE_];
__device__ float g_ecsr[(size_t)NE_ * 4];
__device__ float g_h1[(size_t)NN_ * 256];
__device__ float g_xl2[(size_t)NN_ * 256];
__device__ float g_xr2[(size_t)NN_ * 256];
__device__ float g_h2[(size_t)NN_ * 128];
__device__ float g_sum[256], g_sq[256];
__device__ float g_scale[256], g_shift[256];
__device__ float g_pool[NG_ * 128];
__device__ int   g_count[NG_];

// ---------------- init ----------------
__global__ void k_zero() {
    int i = blockIdx.x * blockDim.x + threadIdx.x;
    int stride = gridDim.x * blockDim.x;
    for (int j = i; j < NN_; j += stride) g_deg[j] = 0;
    for (int j = i; j < NG_ * 128; j += stride) g_pool[j] = 0.f;
    for (int j = i; j < NG_; j += stride) g_count[j] = 0;
    for (int j = i; j < 256; j += stride) { g_sum[j] = 0.f; g_sq[j] = 0.f; }
}

// ---------------- CSR build ----------------
__global__ void k_hist(const int* __restrict__ dst) {
    int e = blockIdx.x * blockDim.x + threadIdx.x;
    if (e < NE_) atomicAdd(&g_deg[dst[e]], 1);
}

__global__ void k_scan() {
    __shared__ int sd[1024];
    __shared__ int carry;
    int tid = threadIdx.x;
    if (tid == 0) carry = 0;
    __syncthreads();
    for (int base = 0; base < NN_; base += 1024) {
        int i = base + tid;
        int v = (i < NN_) ? g_deg[i] : 0;
        sd[tid] = v;
        __syncthreads();
        for (int off = 1; off < 1024; off <<= 1) {
            int t = (tid >= off) ? sd[tid - off] : 0;
            __syncthreads();
            sd[tid] += t;
            __syncthreads();
        }
        int excl = sd[tid] - v + carry;
        if (i < NN_) { g_rowstart[i] = excl; g_cursor[i] = excl; }
        int total = sd[1023];
        __syncthreads();
        if (tid == 0) carry += total;
        __syncthreads();
    }
    if (tid == 0) g_rowstart[NN_] = carry;
}

__global__ void k_scatter(const int* __restrict__ src, const int* __restrict__ dst) {
    int e = blockIdx.x * blockDim.x + threadIdx.x;
    if (e < NE_) {
        int pos = atomicAdd(&g_cursor[dst[e]], 1);
        g_edgepos[e] = pos;
        g_srccsr[pos] = src[e];
    }
}

// ---------------- layer 1: per-edge attention logits (persistent blocks) ----------
__global__ void k_l1_logits(const float* __restrict__ x, const int* __restrict__ src,
                            const int* __restrict__ dst, const float* __restrict__ ea,
                            const float* __restrict__ Wl, const float* __restrict__ bl,
                            const float* __restrict__ Wr, const float* __restrict__ br,
                            const float* __restrict__ We, const float* __restrict__ att) {
    __shared__ float sWl0[256], sWl1[256], sWr0[256], sWr1[256], sbl[256], sbr[256];
    __shared__ float sWe[4][256], satt[256];
    int tid = threadIdx.x;
    sWl0[tid] = Wl[tid]; sWl1[tid] = Wl[256 + tid];
    sWr0[tid] = Wr[tid]; sWr1[tid] = Wr[256 + tid];
    sbl[tid] = bl[tid];  sbr[tid] = br[tid];
    sWe[0][tid] = We[tid]; sWe[1][tid] = We[256 + tid];
    sWe[2][tid] = We[512 + tid]; sWe[3][tid] = We[768 + tid];
    satt[tid] = att[tid];
    __syncthreads();
    int wv = tid >> 6, lane = tid & 63;
    int nw = gridDim.x * 4;
    for (int e = blockIdx.x * 4 + wv; e < NE_; e += nw) {
        int s = src[e], d = dst[e];
        float xs0 = x[2 * s], xs1 = x[2 * s + 1];
        float xd0 = x[2 * d], xd1 = x[2 * d + 1];
        const float4 eav = *reinterpret_cast<const float4*>(ea + 4 * (size_t)e);
        float p[4];
#pragma unroll
        for (int j = 0; j < 4; ++j) {
            int c = j * 64 + lane;
            float z = xs0 * sWl0[c] + xs1 * sWl1[c] + sbl[c]
                    + xd0 * sWr0[c] + xd1 * sWr1[c] + sbr[c]
                    + eav.x * sWe[0][c] + eav.y * sWe[1][c]
                    + eav.z * sWe[2][c] + eav.w * sWe[3][c];
            z = z > 0.f ? z : 0.2f * z;
            p[j] = z * satt[c];
        }
#pragma unroll
        for (int off = 1; off < 64; off <<= 1) {
#pragma unroll
            for (int j = 0; j < 4; ++j) p[j] += __shfl_xor(p[j], off);
        }
        if (lane == 0) {
            float4 v = make_float4(p[0], p[1], p[2], p[3]);
            *reinterpret_cast<float4*>(&g_ecsr[(size_t)g_edgepos[e] * 4]) = v;
        }
    }
}

// ---------------- layer 1: per-node softmax + aggregate ----------------
__global__ void k_l1_agg(const float* __restrict__ x, const float* __restrict__ Wl,
                         const float* __restrict__ bl, const float* __restrict__ bias1) {
    __shared__ float sl[4][MAXD];     // logits per head
    __shared__ float sal[4][MAXD];    // alpha per head
    __shared__ float sx0[MAXD], sx1[MAXD];
    __shared__ float shr[4];          // per-head 1/den and max staging
    int n = blockIdx.x;
    int tid = threadIdx.x;
    int s0 = g_rowstart[n], d = g_rowstart[n + 1] - s0;
    int c = tid, h = c >> 6;
    float wl0 = Wl[c], wl1 = Wl[256 + c], blc = bl[c];

    if (d <= MAXD) {
        for (int i = tid; i < d; i += 256) {
            float4 v = *reinterpret_cast<const float4*>(&g_ecsr[(size_t)(s0 + i) * 4]);
            sl[0][i] = v.x; sl[1][i] = v.y; sl[2][i] = v.z; sl[3][i] = v.w;
            int s = g_srccsr[s0 + i];
            sx0[i] = x[2 * s]; sx1[i] = x[2 * s + 1];
        }
        __syncthreads();
        // wave wv computes alpha for head wv
        int wv = tid >> 6, lane = tid & 63;
        float m = -INFINITY;
        for (int i = lane; i < d; i += 64) m = fmaxf(m, sl[wv][i]);
#pragma unroll
        for (int off = 1; off < 64; off <<= 1) m = fmaxf(m, __shfl_xor(m, off));
        float den = 0.f;
        for (int i = lane; i < d; i += 64) {
            float ex = expf(sl[wv][i] - m);
            sal[wv][i] = ex;
            den += ex;
        }
#pragma unroll
        for (int off = 1; off < 64; off <<= 1) den += __shfl_xor(den, off);
        if (lane == 0) shr[wv] = 1.f / (den + 1e-16f);
        __syncthreads();
        float inv = shr[h];
        float acc = 0.f;
        for (int i = 0; i < d; ++i) {
            float xlv = sx0[i] * wl0 + sx1[i] * wl1 + blc;
            acc += (sal[h][i] * inv) * xlv;
        }
        g_h1[(size_t)n * 256 + c] = acc + bias1[c];
    } else {
        // fallback (should not trigger at these sizes)
        float m = -INFINITY;
        for (int i = 0; i < d; ++i) m = fmaxf(m, g_ecsr[(size_t)(s0 + i) * 4 + h]);
        float den = 0.f;
        for (int i = 0; i < d; ++i) den += expf(g_ecsr[(size_t)(s0 + i) * 4 + h] - m);
        float inv = 1.f / (den + 1e-16f);
        float acc = 0.f;
        for (int i = 0; i < d; ++i) {
            int s = g_srccsr[s0 + i];
            float w = expf(g_ecsr[(size_t)(s0 + i) * 4 + h] - m) * inv;
            acc += w * (x[2 * s] * wl0 + x[2 * s + 1] * wl1 + blc);
        }
        g_h1[(size_t)n * 256 + c] = acc + bias1[c];
    }
}

// ---------------- batchnorm ----------------
template <int C>
__global__ void k_bn_stats() {
    const float* h = (C == 256) ? (const float*)g_h1 : (const float*)g_h2;
    int c = threadIdx.x;
    int r0 = blockIdx.x * 100;
    float s = 0.f, ss = 0.f;
    for (int r = 0; r < 100; ++r) {
        float v = h[(size_t)(r0 + r) * C + c];
        s += v; ss += v * v;
    }
    atomicAdd(&g_sum[c], s);
    atomicAdd(&g_sq[c], ss);
}

template <int C>
__global__ void k_bn_finalize(const float* __restrict__ g, const float* __restrict__ b) {
    int c = threadIdx.x;
    float mu = g_sum[c] / (float)NN_;
    float var = g_sq[c] / (float)NN_ - mu * mu;
    float sc = g[c] * rsqrtf(var + 1e-5f);
    g_scale[c] = sc;
    g_shift[c] = b[c] - mu * sc;
    g_sum[c] = 0.f; g_sq[c] = 0.f;  // ready for next BN
}

template <int C>
__global__ void k_bn_apply() {
    float* h = (C == 256) ? (float*)g_h1 : (float*)g_h2;
    int i = blockIdx.x * blockDim.x + threadIdx.x;
    int stride = gridDim.x * blockDim.x;
    for (int j = i; j < NN_ * C; j += stride) {
        int c = j & (C - 1);
        float v = h[j] * g_scale[c] + g_shift[c];
        h[j] = v > 0.f ? v : expm1f(v);
    }
}

// ---------------- SGEMM: (40000x256) @ (256x256) + bias -> g_xl2 / g_xr2 ----------
__global__ void k_gemm(const float* __restrict__ W, const float* __restrict__ bias, int sel) {
    const float* A = g_h1;
    float* C = sel ? g_xr2 : g_xl2;
    const int K = 256, NNc = 256;
    __shared__ float As[32][65];   // As[k][m] (transposed, +1 pad)
    __shared__ float Bs[32][64];   // Bs[k][n]
    int tid = threadIdx.x;
    int tx = tid & 15, ty = tid >> 4;
    int m0 = blockIdx.x * 64, n0 = blockIdx.y * 64;
    int la_r = tid >> 2;            // 0..63 row (m)
    int la_c = (tid & 3) * 8;       // k offset
    int lb_r = tid >> 3;            // 0..31 (k)
    int lb_c = (tid & 7) * 8;       // n offset
    float acc[4][4] = {};
    for (int k0 = 0; k0 < K; k0 += 32) {
        const float4* Ap = reinterpret_cast<const float4*>(A + (size_t)(m0 + la_r) * K + k0 + la_c);
        float4 a0 = Ap[0], a1 = Ap[1];
        As[la_c + 0][la_r] = a0.x; As[la_c + 1][la_r] = a0.y;
        As[la_c + 2][la_r] = a0.z; As[la_c + 3][la_r] = a0.w;
        As[la_c + 4][la_r] = a1.x; As[la_c + 5][la_r] = a1.y;
        As[la_c + 6][la_r] = a1.z; As[la_c + 7][la_r] = a1.w;
        const float4* Wp = reinterpret_cast<const float4*>(W + (size_t)(k0 + lb_r) * NNc + n0 + lb_c);
        *reinterpret_cast<float4*>(&Bs[lb_r][lb_c]) = Wp[0];
        *reinterpret_cast<float4*>(&Bs[lb_r][lb_c + 4]) = Wp[1];
        __syncthreads();
#pragma unroll
        for (int k = 0; k < 32; ++k) {
            float a[4], b[4];
#pragma unroll
            for (int i = 0; i < 4; ++i) a[i] = As[k][ty * 4 + i];
#pragma unroll
            for (int j = 0; j < 4; ++j) b[j] = Bs[k][tx * 4 + j];
#pragma unroll
            for (int i = 0; i < 4; ++i)
#pragma unroll
                for (int j = 0; j < 4; ++j) acc[i][j] += a[i] * b[j];
        }
        __syncthreads();
    }
#pragma unroll
    for (int i = 0; i < 4; ++i) {
        int m = m0 + ty * 4 + i;
#pragma unroll
        for (int j = 0; j < 4; ++j) {
            int n = n0 + tx * 4 + j;
            C[(size_t)m * NNc + n] = acc[i][j] + bias[n];
        }
    }
}

// ---------------- layer 2: per-edge attention logits (persistent blocks) ----------
__global__ void k_l2_logits(const int* __restrict__ src, const int* __restrict__ dst,
                            const float* __restrict__ ea, const float* __restrict__ We,
                            const float* __restrict__ att) {
    __shared__ float sWe[4][256], satt[256];
    int tid = threadIdx.x;
    sWe[0][tid] = We[tid]; sWe[1][tid] = We[256 + tid];
    sWe[2][tid] = We[512 + tid]; sWe[3][tid] = We[768 + tid];
    satt[tid] = att[tid];
    __syncthreads();
    int wv = tid >> 6, lane = tid & 63;
    int nw = gridDim.x * 4;
    for (int e = blockIdx.x * 4 + wv; e < NE_; e += nw) {
        int s = src[e], d = dst[e];
        const float4 eav = *reinterpret_cast<const float4*>(ea + 4 * (size_t)e);
        float p[4];
#pragma unroll
        for (int j = 0; j < 4; ++j) {
            int c = j * 64 + lane;
            float z = g_xl2[(size_t)s * 256 + c] + g_xr2[(size_t)d * 256 + c]
                    + eav.x * sWe[0][c] + eav.y * sWe[1][c]
                    + eav.z * sWe[2][c] + eav.w * sWe[3][c];
            z = z > 0.f ? z : 0.2f * z;
            p[j] = z * satt[c];
        }
        float p0 = p[0] + p[1], p1 = p[2] + p[3];  // head0 = c<128, head1 = c>=128
#pragma unroll
        for (int off = 1; off < 64; off <<= 1) {
            p0 += __shfl_xor(p0, off);
            p1 += __shfl_xor(p1, off);
        }
        if (lane == 0) {
            float2 v = make_float2(p0, p1);
            *reinterpret_cast<float2*>(&g_ecsr[(size_t)g_edgepos[e] * 2]) = v;
        }
    }
}

// ---------------- layer 2: per-node softmax + aggregate + head-mean ----------------
__global__ void k_l2_agg(const float* __restrict__ bias2) {
    __shared__ float sl[2][MAXD];
    __shared__ float sal[2][MAXD];
    __shared__ int   ssrc[MAXD];
    __shared__ float shr[2];
    __shared__ float tmp[256];
    int n = blockIdx.x;
    int tid = threadIdx.x;
    int s0 = g_rowstart[n], d = g_rowstart[n + 1] - s0;
    int c = tid, h = c >> 7;

    if (d <= MAXD) {
        for (int i = tid; i < d; i += 256) {
            float2 v = *reinterpret_cast<const float2*>(&g_ecsr[(size_t)(s0 + i) * 2]);
            sl[0][i] = v.x; sl[1][i] = v.y;
            ssrc[i] = g_srccsr[s0 + i];
        }
        __syncthreads();
        int wv = tid >> 6, lane = tid & 63;
        if (wv < 2) {
            float m = -INFINITY;
            for (int i = lane; i < d; i += 64) m = fmaxf(m, sl[wv][i]);
#pragma unroll
            for (int off = 1; off < 64; off <<= 1) m = fmaxf(m, __shfl_xor(m, off));
            float den = 0.f;
            for (int i = lane; i < d; i += 64) {
                float ex = expf(sl[wv][i] - m);
                sal[wv][i] = ex;
                den += ex;
            }
#pragma unroll
            for (int off = 1; off < 64; off <<= 1) den += __shfl_xor(den, off);
            if (lane == 0) shr[wv] = 1.f / (den + 1e-16f);
        }
        __syncthreads();
        float inv = shr[h];
        float acc = 0.f;
        for (int i = 0; i < d; ++i) {
            acc += (sal[h][i] * inv) * g_xl2[(size_t)ssrc[i] * 256 + c];
        }
        tmp[c] = acc;
        __syncthreads();
        if (c < 128) g_h2[(size_t)n * 128 + c] = 0.5f * (tmp[c] + tmp[c + 128]) + bias2[c];
    } else {
        float m = -INFINITY;
        for (int i = 0; i < d; ++i) m = fmaxf(m, g_ecsr[(size_t)(s0 + i) * 2 + h]);
        float den = 0.f;
        for (int i = 0; i < d; ++i) den += expf(g_ecsr[(size_t)(s0 + i) * 2 + h] - m);
        float inv = 1.f / (den + 1e-16f);
        float acc = 0.f;
        for (int i = 0; i < d; ++i) {
            int s = g_srccsr[s0 + i];
            float w = expf(g_ecsr[(size_t)(s0 + i) * 2 + h] - m) * inv;
            acc += w * g_xl2[(size_t)s * 256 + c];
        }
        tmp[c] = acc;
        __syncthreads();
        if (c < 128) g_h2[(size_t)n * 128 + c] = 0.5f * (tmp[c] + tmp[c + 128]) + bias2[c];
    }
}

// ---------------- global mean pool ----------------
__global__ void k_pool(const int* __restrict__ batch) {
    int i = blockIdx.x * blockDim.x + threadIdx.x;
    int stride = gridDim.x * blockDim.x;
    for (int j = i; j < NN_ * 128; j += stride) {
        int n = j >> 7, c = j & 127;
        int b = batch[n];
        atomicAdd(&g_pool[b * 128 + c], g_h2[j]);
        if (c == 0) atomicAdd(&g_count[b], 1);
    }
}

// ---------------- MLP head ----------------
__global__ void k_head(const float* __restrict__ W1, const float* __restrict__ b1,
                       const float* __restrict__ W2, const float* __restrict__ b2,
                       float* __restrict__ out) {
    int g = blockIdx.x, t = threadIdx.x;  // 64 threads
    __shared__ float p[128], hm[64];
    float cnt = fmaxf((float)g_count[g], 1.f);
    float inv = 1.f / cnt;
    p[t] = g_pool[g * 128 + t] * inv;
    p[t + 64] = g_pool[g * 128 + 64 + t] * inv;
    __syncthreads();
    float a = b1[t];
    for (int k = 0; k < 128; ++k) a += p[k] * W1[k * 64 + t];
    hm[t] = a > 0.f ? a : expm1f(a);
    __syncthreads();
    if (t < 12) {
        float o = b2[t];
        for (int k = 0; k < 64; ++k) o += hm[k] * W2[k * 12 + t];
        out[g * 12 + t] = o;
    }
}

// ---------------- launch ----------------
extern "C" void kernel_launch(void* const* d_in, const int* in_sizes, int n_in,
                              void* d_out, int out_size, void* d_ws, size_t ws_size,
                              hipStream_t stream) {
    const float* x     = (const float*)d_in[0];
    const int*   ei    = (const int*)d_in[1];
    const float* ea    = (const float*)d_in[2];
    const int*   batch = (const int*)d_in[3];
    const float* Wl1   = (const float*)d_in[4];
    const float* bl1   = (const float*)d_in[5];
    const float* Wr1   = (const float*)d_in[6];
    const float* br1   = (const float*)d_in[7];
    const float* We1   = (const float*)d_in[8];
    const float* att1  = (const float*)d_in[9];
    const float* bias1 = (const float*)d_in[10];
    const float* g1    = (const float*)d_in[11];
    const float* be1   = (const float*)d_in[12];
    const float* Wl2   = (const float*)d_in[13];
    const float* bl2   = (const float*)d_in[14];
    const float* Wr2   = (const float*)d_in[15];
    const float* br2   = (const float*)d_in[16];
    const float* We2   = (const float*)d_in[17];
    const float* att2  = (const float*)d_in[18];
    const float* bias2 = (const float*)d_in[19];
    const float* g2    = (const float*)d_in[20];
    const float* be2   = (const float*)d_in[21];
    const float* Wlin1 = (const float*)d_in[22];
    const float* blin1 = (const float*)d_in[23];
    const float* Wlin2 = (const float*)d_in[24];
    const float* blin2 = (const float*)d_in[25];
    float* out = (float*)d_out;
    const int* src = ei;
    const int* dst = ei + NE_;

    k_zero<<<256, 256, 0, stream>>>();
    k_hist<<<2500, 256, 0, stream>>>(dst);
    k_scan<<<1, 1024, 0, stream>>>();
    k_scatter<<<2500, 256, 0, stream>>>(src, dst);

    // layer 1
    k_l1_logits<<<1280, 256, 0, stream>>>(x, src, dst, ea, Wl1, bl1, Wr1, br1, We1, att1);
    k_l1_agg<<<40000, 256, 0, stream>>>(x, Wl1, bl1, bias1);
    k_bn_stats<256><<<400, 256, 0, stream>>>();
    k_bn_finalize<256><<<1, 256, 0, stream>>>(g1, be1);
    k_bn_apply<256><<<4096, 256, 0, stream>>>();

    // layer 2 projections
    k_gemm<<<dim3(625, 4), 256, 0, stream>>>(Wl2, bl2, 0);
    k_gemm<<<dim3(625, 4), 256, 0, stream>>>(Wr2, br2, 1);

    // layer 2
    k_l2_logits<<<1280, 256, 0, stream>>>(src, dst, ea, We2, att2);
    k_l2_agg<<<40000, 256, 0, stream>>>(bias2);
    k_bn_stats<128><<<400, 128, 0, stream>>>();
    k_bn_finalize<128><<<1, 128, 0, stream>>>(g2, be2);
    k_bn_apply<128><<<4096, 256, 0, stream>>>();

    // pool + head
    k_pool<<<2048, 256, 0, stream>>>(batch);
    k_head<<<NG_, 64, 0, stream>>>(Wlin1, blin1, Wlin2, blin2, out);
}

// Round 5
// 764.384 us; speedup vs baseline: 2.0430x; 1.3599x over previous
//
#include <hip/hip_runtime.h>
#include <math.h>

#define NN_ 40000
#define NE_ 640000
#define NG_ 400
#define CH_ 64           // softmax chunk (online-softmax handles d > CH_ correctly)
#define NBLK_SCAN 157    // ceil(40000/256)

typedef unsigned short ushort_t;

// ---------------- device scratch ----------------
// NOTE: __device__ globals must NEVER be passed as kernel arguments from host
// (host sees shadow symbol address -> GPU fault). Always bind inside kernels.
__device__ int    g_deg[NN_];
__device__ int    g_rowstart[NN_ + 1];
__device__ int    g_cursor[NN_];
__device__ int    g_srccsr[NE_];
__device__ float4 g_eacsr[NE_];
__device__ int    g_bsum[NBLK_SCAN], g_boff[NBLK_SCAN];
__device__ ushort_t g_xl1[(size_t)NN_ * 256];
__device__ ushort_t g_xr1[(size_t)NN_ * 256];
__device__ ushort_t g_xl2[(size_t)NN_ * 256];
__device__ ushort_t g_xr2[(size_t)NN_ * 256];
__device__ float  g_h1[(size_t)NN_ * 256];
__device__ float  g_h2[(size_t)NN_ * 128];
__device__ float  g_sum[256], g_sq[256];
__device__ float  g_scale[256], g_shift[256];
__device__ float  g_pool[NG_ * 128];
__device__ int    g_count[NG_];

// bf16 helpers: arrays of ushort bf16, accessed pairwise via uint
__device__ __forceinline__ float bflo(unsigned int q) { return __uint_as_float(q << 16); }
__device__ __forceinline__ float bfhi(unsigned int q) { return __uint_as_float(q & 0xFFFF0000u); }
__device__ __forceinline__ float bf2f(ushort_t u) { return __uint_as_float(((unsigned int)u) << 16); }
__device__ __forceinline__ unsigned int f2bf(float f) {
    unsigned int u = __float_as_uint(f);
    return (u + 0x7FFFu + ((u >> 16) & 1u)) >> 16;
}
__device__ __forceinline__ unsigned int pack2(float a, float b) {
    return f2bf(a) | (f2bf(b) << 16);
}

// ---------------- init ----------------
__global__ void k_zero() {
    int i = blockIdx.x * blockDim.x + threadIdx.x;
    int stride = gridDim.x * blockDim.x;
    for (int j = i; j < NN_; j += stride) g_deg[j] = 0;
    for (int j = i; j < 256; j += stride) { g_sum[j] = 0.f; g_sq[j] = 0.f; }
}

// ---------------- CSR build ----------------
__global__ void k_hist(const int* __restrict__ dst) {
    int e = blockIdx.x * blockDim.x + threadIdx.x;
    if (e < NE_) atomicAdd(&g_deg[dst[e]], 1);
}

__global__ void k_scan1() {
    __shared__ int sd[256];
    int b = blockIdx.x, t = threadIdx.x, i = b * 256 + t;
    int v = (i < NN_) ? g_deg[i] : 0;
    sd[t] = v;
    __syncthreads();
    for (int off = 1; off < 256; off <<= 1) {
        int tv = (t >= off) ? sd[t - off] : 0;
        __syncthreads();
        sd[t] += tv;
        __syncthreads();
    }
    if (i < NN_) g_rowstart[i] = sd[t] - v;   // block-local exclusive
    if (t == 255) g_bsum[b] = sd[255];
}

__global__ void k_scan2() {
    __shared__ int sd[256];
    int t = threadIdx.x;
    int v = (t < NBLK_SCAN) ? g_bsum[t] : 0;
    sd[t] = v;
    __syncthreads();
    for (int off = 1; off < 256; off <<= 1) {
        int tv = (t >= off) ? sd[t - off] : 0;
        __syncthreads();
        sd[t] += tv;
        __syncthreads();
    }
    if (t < NBLK_SCAN) g_boff[t] = sd[t] - v;
    if (t == 255) g_rowstart[NN_] = sd[255];
}

__global__ void k_scan3() {
    int i = blockIdx.x * blockDim.x + threadIdx.x;
    if (i < NN_) {
        int r = g_rowstart[i] + g_boff[i >> 8];
        g_rowstart[i] = r;
        g_cursor[i] = r;
    }
}

__global__ void k_scatter(const int* __restrict__ src, const int* __restrict__ dst,
                          const float* __restrict__ ea) {
    int e = blockIdx.x * blockDim.x + threadIdx.x;
    if (e < NE_) {
        int pos = atomicAdd(&g_cursor[dst[e]], 1);
        g_srccsr[pos] = src[e];
        g_eacsr[pos] = reinterpret_cast<const float4*>(ea)[e];
    }
}

// ---------------- layer-1 node transforms: xl1/xr1 = x@W + b (bf16 out) ----------
__global__ void k_xform1(const float* __restrict__ x,
                         const float* __restrict__ Wl, const float* __restrict__ bl,
                         const float* __restrict__ Wr, const float* __restrict__ br) {
    int n = blockIdx.x * 4 + (threadIdx.x >> 6);
    int lane = threadIdx.x & 63;
    if (n >= NN_) return;
    float x0 = x[2 * n], x1 = x[2 * n + 1];
    int c4 = lane * 4;
    float l0 = x0 * Wl[c4 + 0] + x1 * Wl[256 + c4 + 0] + bl[c4 + 0];
    float l1 = x0 * Wl[c4 + 1] + x1 * Wl[256 + c4 + 1] + bl[c4 + 1];
    float l2 = x0 * Wl[c4 + 2] + x1 * Wl[256 + c4 + 2] + bl[c4 + 2];
    float l3 = x0 * Wl[c4 + 3] + x1 * Wl[256 + c4 + 3] + bl[c4 + 3];
    float r0 = x0 * Wr[c4 + 0] + x1 * Wr[256 + c4 + 0] + br[c4 + 0];
    float r1 = x0 * Wr[c4 + 1] + x1 * Wr[256 + c4 + 1] + br[c4 + 1];
    float r2 = x0 * Wr[c4 + 2] + x1 * Wr[256 + c4 + 2] + br[c4 + 2];
    float r3 = x0 * Wr[c4 + 3] + x1 * Wr[256 + c4 + 3] + br[c4 + 3];
    *reinterpret_cast<uint2*>(g_xl1 + (size_t)n * 256 + c4) = make_uint2(pack2(l0, l1), pack2(l2, l3));
    *reinterpret_cast<uint2*>(g_xr1 + (size_t)n * 256 + c4) = make_uint2(pack2(r0, r1), pack2(r2, r3));
}

// ---------------- fused GATv2 layer: logits + softmax + aggregate ----------------
// One block (256 thr) per destination node. D = H*C = 256 always.
// Globals bound INSIDE the kernel via LAYER (compile-time), never passed from host.
template <int LAYER>
__global__ void k_gat(const float* __restrict__ att, const float* __restrict__ We,
                      const float* __restrict__ bias) {
    constexpr int H = (LAYER == 1) ? 4 : 2;
    constexpr int C = (LAYER == 1) ? 64 : 128;
    constexpr bool CONCAT = (LAYER == 1);
    constexpr int GL = C / 4;           // lanes per head group in phase A
    const ushort_t* __restrict__ xl = (LAYER == 1) ? g_xl1 : g_xl2;
    const ushort_t* __restrict__ xr = (LAYER == 1) ? g_xr1 : g_xr2;
    float* __restrict__ hout = (LAYER == 1) ? g_h1 : g_h2;

    __shared__ float slog[H][CH_];
    __shared__ float sw[H][CH_];
    __shared__ int   ssrc[CH_];
    __shared__ float sscale[H], sinv[H];
    __shared__ float stmp[256];

    int n = blockIdx.x;
    int tid = threadIdx.x;
    int wv = tid >> 6, lane = tid & 63;
    int h = tid / C;
    int c4 = lane * 4;

    // per-lane constants (scalar loads; no alignment assumptions on params)
    float a0 = att[c4], a1 = att[c4 + 1], a2c = att[c4 + 2], a3 = att[c4 + 3];
    float we00 = We[c4], we01 = We[c4 + 1], we02 = We[c4 + 2], we03 = We[c4 + 3];
    float we10 = We[256 + c4], we11 = We[256 + c4 + 1], we12 = We[256 + c4 + 2], we13 = We[256 + c4 + 3];
    float we20 = We[512 + c4], we21 = We[512 + c4 + 1], we22 = We[512 + c4 + 2], we23 = We[512 + c4 + 3];
    float we30 = We[768 + c4], we31 = We[768 + c4 + 1], we32 = We[768 + c4 + 2], we33 = We[768 + c4 + 3];
    uint2 xq = *reinterpret_cast<const uint2*>(xr + (size_t)n * 256 + c4);
    float xr0 = bflo(xq.x), xr1 = bfhi(xq.x), xr2 = bflo(xq.y), xr3 = bfhi(xq.y);

    int s0 = g_rowstart[n];
    int dtot = g_rowstart[n + 1] - s0;

    float mrun = -INFINITY, den = 0.f;   // live in wave-h lanes (wv < H)
    float acc = 0.f;                      // per-thread channel accumulator

    for (int c0 = 0; c0 < dtot; c0 += CH_) {
        int dc = min(CH_, dtot - c0);
        // ---- phase A: edge-per-wave logits ----
        for (int i = wv; i < dc; i += 4) {
            int s = g_srccsr[s0 + c0 + i];
            if (lane == 0) ssrc[i] = s;
            float4 ea4 = g_eacsr[s0 + c0 + i];
            uint2 xlq = *reinterpret_cast<const uint2*>(xl + (size_t)s * 256 + c4);
            float z0 = bflo(xlq.x) + xr0 + ea4.x * we00 + ea4.y * we10 + ea4.z * we20 + ea4.w * we30;
            float z1 = bfhi(xlq.x) + xr1 + ea4.x * we01 + ea4.y * we11 + ea4.z * we21 + ea4.w * we31;
            float z2 = bflo(xlq.y) + xr2 + ea4.x * we02 + ea4.y * we12 + ea4.z * we22 + ea4.w * we32;
            float z3 = bfhi(xlq.y) + xr3 + ea4.x * we03 + ea4.y * we13 + ea4.z * we23 + ea4.w * we33;
            z0 = fmaxf(z0, 0.2f * z0); z1 = fmaxf(z1, 0.2f * z1);
            z2 = fmaxf(z2, 0.2f * z2); z3 = fmaxf(z3, 0.2f * z3);
            float t = z0 * a0 + z1 * a1 + z2 * a2c + z3 * a3;
#pragma unroll
            for (int off = 1; off < GL; off <<= 1) t += __shfl_xor(t, off);
            if ((lane & (GL - 1)) == 0) slog[lane / GL][i] = t;
        }
        __syncthreads();
        // ---- phase B: online softmax (wave per head) ----
        if (wv < H) {
            float mc = -INFINITY;
            for (int i = lane; i < dc; i += 64) mc = fmaxf(mc, slog[wv][i]);
#pragma unroll
            for (int off = 1; off < 64; off <<= 1) mc = fmaxf(mc, __shfl_xor(mc, off));
            float mnew = fmaxf(mrun, mc);
            float sc = expf(mrun - mnew);
            float dl = 0.f;
            for (int i = lane; i < dc; i += 64) {
                float w = expf(slog[wv][i] - mnew);
                sw[wv][i] = w;
                dl += w;
            }
#pragma unroll
            for (int off = 1; off < 64; off <<= 1) dl += __shfl_xor(dl, off);
            den = den * sc + dl;
            mrun = mnew;
            if (lane == 0) sscale[wv] = sc;
        }
        __syncthreads();
        // ---- phase C: weighted aggregate (xl rows L1/L2-hot from phase A) ----
        float scl = sscale[h];
        float a2 = 0.f;
        for (int i = 0; i < dc; ++i)
            a2 = fmaf(sw[h][i], bf2f(xl[(size_t)ssrc[i] * 256 + tid]), a2);
        acc = acc * scl + a2;
        __syncthreads();
    }
    if (wv < H && lane == 0) sinv[wv] = 1.f / (den + 1e-16f);
    __syncthreads();
    float outv = acc * sinv[h];
    if (CONCAT) {
        hout[(size_t)n * 256 + tid] = outv + bias[tid];
    } else {
        stmp[tid] = outv;
        __syncthreads();
        if (tid < C) hout[(size_t)n * C + tid] = 0.5f * (stmp[tid] + stmp[tid + C]) + bias[tid];
    }
}

// ---------------- batchnorm ----------------
template <int C>
__global__ void k_bn_stats() {
    const float* h = (C == 256) ? (const float*)g_h1 : (const float*)g_h2;
    int c = threadIdx.x;
    int r0 = blockIdx.x * 100;
    float s = 0.f, ss = 0.f;
    for (int r = 0; r < 100; ++r) {
        float v = h[(size_t)(r0 + r) * C + c];
        s += v; ss += v * v;
    }
    atomicAdd(&g_sum[c], s);
    atomicAdd(&g_sq[c], ss);
}

template <int C>
__global__ void k_bn_finalize(const float* __restrict__ g, const float* __restrict__ b) {
    int c = threadIdx.x;
    float mu = g_sum[c] / (float)NN_;
    float var = g_sq[c] / (float)NN_ - mu * mu;
    float sc = g[c] * rsqrtf(var + 1e-5f);
    g_scale[c] = sc;
    g_shift[c] = b[c] - mu * sc;
    g_sum[c] = 0.f; g_sq[c] = 0.f;
}

template <int C>
__global__ void k_bn_apply() {
    float* h = (C == 256) ? (float*)g_h1 : (float*)g_h2;
    int i = blockIdx.x * blockDim.x + threadIdx.x;
    int stride = gridDim.x * blockDim.x;
    for (int j = i; j < NN_ * C; j += stride) {
        int c = j & (C - 1);
        float v = h[j] * g_scale[c] + g_shift[c];
        h[j] = v > 0.f ? v : expm1f(v);
    }
}

// ---------------- SGEMM: g_h1(40000x256) @ W(256x256) + bias -> bf16 out ----------
// sel picks destination INSIDE the kernel (device globals, r2-proven pattern)
__global__ void k_gemm(const float* __restrict__ W, const float* __restrict__ bias, int sel) {
    const float* A = g_h1;
    ushort_t* Cb = sel ? g_xr2 : g_xl2;
    const int K = 256, NNc = 256;
    __shared__ float As[32][65];
    __shared__ float Bs[32][64];
    int tid = threadIdx.x;
    int tx = tid & 15, ty = tid >> 4;
    int m0 = blockIdx.x * 64, n0 = blockIdx.y * 64;
    int la_r = tid >> 2;
    int la_c = (tid & 3) * 8;
    int lb_r = tid >> 3;
    int lb_c = (tid & 7) * 8;
    float acc[4][4] = {};
    for (int k0 = 0; k0 < K; k0 += 32) {
        const float4* Ap = reinterpret_cast<const float4*>(A + (size_t)(m0 + la_r) * K + k0 + la_c);
        float4 a0 = Ap[0], a1 = Ap[1];
        As[la_c + 0][la_r] = a0.x; As[la_c + 1][la_r] = a0.y;
        As[la_c + 2][la_r] = a0.z; As[la_c + 3][la_r] = a0.w;
        As[la_c + 4][la_r] = a1.x; As[la_c + 5][la_r] = a1.y;
        As[la_c + 6][la_r] = a1.z; As[la_c + 7][la_r] = a1.w;
        const float4* Wp = reinterpret_cast<const float4*>(W + (size_t)(k0 + lb_r) * NNc + n0 + lb_c);
        *reinterpret_cast<float4*>(&Bs[lb_r][lb_c]) = Wp[0];
        *reinterpret_cast<float4*>(&Bs[lb_r][lb_c + 4]) = Wp[1];
        __syncthreads();
#pragma unroll
        for (int k = 0; k < 32; ++k) {
            float a[4], b[4];
#pragma unroll
            for (int i = 0; i < 4; ++i) a[i] = As[k][ty * 4 + i];
#pragma unroll
            for (int j = 0; j < 4; ++j) b[j] = Bs[k][tx * 4 + j];
#pragma unroll
            for (int i = 0; i < 4; ++i)
#pragma unroll
                for (int j = 0; j < 4; ++j) acc[i][j] += a[i] * b[j];
        }
        __syncthreads();
    }
    float b0 = bias[n0 + tx * 4 + 0], b1 = bias[n0 + tx * 4 + 1];
    float b2 = bias[n0 + tx * 4 + 2], b3 = bias[n0 + tx * 4 + 3];
#pragma unroll
    for (int i = 0; i < 4; ++i) {
        int m = m0 + ty * 4 + i;
        uint2 u = make_uint2(pack2(acc[i][0] + b0, acc[i][1] + b1),
                             pack2(acc[i][2] + b2, acc[i][3] + b3));
        *reinterpret_cast<uint2*>(Cb + (size_t)m * NNc + n0 + tx * 4) = u;
    }
}

// ---------------- global mean pool (batch is sorted -> block per graph) ----------
__global__ void k_pool2(const int* __restrict__ batch) {
    int g = blockIdx.x, t = threadIdx.x;  // 128 threads
    __shared__ int sbeg, send;
    if (t == 0) {
        int lo = 0, hi = NN_;
        while (lo < hi) { int mid = (lo + hi) >> 1; if (batch[mid] < g) lo = mid + 1; else hi = mid; }
        sbeg = lo;
    }
    if (t == 1) {
        int lo = 0, hi = NN_;
        while (lo < hi) { int mid = (lo + hi) >> 1; if (batch[mid] <= g) lo = mid + 1; else hi = mid; }
        send = lo;
    }
    __syncthreads();
    int beg = sbeg, end = send;
    float acc = 0.f;
    for (int n = beg; n < end; ++n) acc += g_h2[(size_t)n * 128 + t];
    g_pool[g * 128 + t] = acc;
    if (t == 0) g_count[g] = end - beg;
}

// ---------------- MLP head ----------------
__global__ void k_head(const float* __restrict__ W1, const float* __restrict__ b1,
                       const float* __restrict__ W2, const float* __restrict__ b2,
                       float* __restrict__ out) {
    int g = blockIdx.x, t = threadIdx.x;  // 64 threads
    __shared__ float p[128], hm[64];
    float cnt = fmaxf((float)g_count[g], 1.f);
    float inv = 1.f / cnt;
    p[t] = g_pool[g * 128 + t] * inv;
    p[t + 64] = g_pool[g * 128 + 64 + t] * inv;
    __syncthreads();
    float a = b1[t];
    for (int k = 0; k < 128; ++k) a += p[k] * W1[k * 64 + t];
    hm[t] = a > 0.f ? a : expm1f(a);
    __syncthreads();
    if (t < 12) {
        float o = b2[t];
        for (int k = 0; k < 64; ++k) o += hm[k] * W2[k * 12 + t];
        out[g * 12 + t] = o;
    }
}

// ---------------- launch ----------------
extern "C" void kernel_launch(void* const* d_in, const int* in_sizes, int n_in,
                              void* d_out, int out_size, void* d_ws, size_t ws_size,
                              hipStream_t stream) {
    const float* x     = (const float*)d_in[0];
    const int*   ei    = (const int*)d_in[1];
    const float* ea    = (const float*)d_in[2];
    const int*   batch = (const int*)d_in[3];
    const float* Wl1   = (const float*)d_in[4];
    const float* bl1   = (const float*)d_in[5];
    const float* Wr1   = (const float*)d_in[6];
    const float* br1   = (const float*)d_in[7];
    const float* We1   = (const float*)d_in[8];
    const float* att1  = (const float*)d_in[9];
    const float* bias1 = (const float*)d_in[10];
    const float* g1    = (const float*)d_in[11];
    const float* be1   = (const float*)d_in[12];
    const float* Wl2   = (const float*)d_in[13];
    const float* bl2   = (const float*)d_in[14];
    const float* Wr2   = (const float*)d_in[15];
    const float* br2   = (const float*)d_in[16];
    const float* We2   = (const float*)d_in[17];
    const float* att2  = (const float*)d_in[18];
    const float* bias2 = (const float*)d_in[19];
    const float* g2    = (const float*)d_in[20];
    const float* be2   = (const float*)d_in[21];
    const float* Wlin1 = (const float*)d_in[22];
    const float* blin1 = (const float*)d_in[23];
    const float* Wlin2 = (const float*)d_in[24];
    const float* blin2 = (const float*)d_in[25];
    float* out = (float*)d_out;
    const int* src = ei;
    const int* dst = ei + NE_;

    k_zero<<<256, 256, 0, stream>>>();
    k_hist<<<2500, 256, 0, stream>>>(dst);
    k_scan1<<<NBLK_SCAN, 256, 0, stream>>>();
    k_scan2<<<1, 256, 0, stream>>>();
    k_scan3<<<NBLK_SCAN, 256, 0, stream>>>();
    k_scatter<<<2500, 256, 0, stream>>>(src, dst, ea);

    // layer 1
    k_xform1<<<10000, 256, 0, stream>>>(x, Wl1, bl1, Wr1, br1);
    k_gat<1><<<NN_, 256, 0, stream>>>(att1, We1, bias1);
    k_bn_stats<256><<<400, 256, 0, stream>>>();
    k_bn_finalize<256><<<1, 256, 0, stream>>>(g1, be1);
    k_bn_apply<256><<<4096, 256, 0, stream>>>();

    // layer 2 projections (fp32 in, bf16 out)
    k_gemm<<<dim3(625, 4), 256, 0, stream>>>(Wl2, bl2, 0);
    k_gemm<<<dim3(625, 4), 256, 0, stream>>>(Wr2, br2, 1);

    // layer 2
    k_gat<2><<<NN_, 256, 0, stream>>>(att2, We2, bias2);
    k_bn_stats<128><<<400, 128, 0, stream>>>();
    k_bn_finalize<128><<<1, 128, 0, stream>>>(g2, be2);
    k_bn_apply<128><<<4096, 256, 0, stream>>>();

    // pool + head
    k_pool2<<<NG_, 128, 0, stream>>>(batch);
    k_head<<<NG_, 64, 0, stream>>>(Wlin1, blin1, Wlin2, blin2, out);
}

// Round 6
// 675.424 us; speedup vs baseline: 2.3121x; 1.1317x over previous
//
#include <hip/hip_runtime.h>
#include <math.h>

#define NN_ 40000
#define NE_ 640000
#define NG_ 400
#define CH_ 32           // softmax chunk (online-softmax handles d > CH_ correctly)
#define NBLK_SCAN 157    // ceil(40000/256)

typedef unsigned short ushort_t;

// ---------------- device scratch ----------------
// NOTE: __device__ globals must NEVER be passed as kernel arguments from host
// (host sees shadow symbol address -> GPU fault). Always bind inside kernels.
__device__ int    g_deg[NN_];
__device__ int    g_rowstart[NN_ + 1];
__device__ int    g_cursor[NN_];
__device__ int    g_srccsr[NE_];
__device__ float4 g_eacsr[NE_];
__device__ int    g_bsum[NBLK_SCAN], g_boff[NBLK_SCAN];
__device__ ushort_t g_xl1[(size_t)NN_ * 256];
__device__ ushort_t g_xr1[(size_t)NN_ * 256];
__device__ ushort_t g_xl2[(size_t)NN_ * 256];
__device__ ushort_t g_xr2[(size_t)NN_ * 256];
__device__ float  g_h1[(size_t)NN_ * 256];
__device__ float  g_h2[(size_t)NN_ * 128];
__device__ float  g_sum[256], g_sq[256];
__device__ float  g_scale[256], g_shift[256];
__device__ float  g_pool[NG_ * 128];
__device__ int    g_count[NG_];

// bf16 helpers: arrays of ushort bf16, accessed pairwise via uint
__device__ __forceinline__ float bflo(unsigned int q) { return __uint_as_float(q << 16); }
__device__ __forceinline__ float bfhi(unsigned int q) { return __uint_as_float(q & 0xFFFF0000u); }
__device__ __forceinline__ float bf2f(ushort_t u) { return __uint_as_float(((unsigned int)u) << 16); }
__device__ __forceinline__ unsigned int f2bf(float f) {
    unsigned int u = __float_as_uint(f);
    return (u + 0x7FFFu + ((u >> 16) & 1u)) >> 16;
}
__device__ __forceinline__ unsigned int pack2(float a, float b) {
    return f2bf(a) | (f2bf(b) << 16);
}

// ---------------- init ----------------
__global__ void k_zero() {
    int i = blockIdx.x * blockDim.x + threadIdx.x;
    int stride = gridDim.x * blockDim.x;
    for (int j = i; j < NN_; j += stride) g_deg[j] = 0;
    for (int j = i; j < 256; j += stride) { g_sum[j] = 0.f; g_sq[j] = 0.f; }
}

// ---------------- CSR build ----------------
__global__ void k_hist(const int* __restrict__ dst) {
    int e = blockIdx.x * blockDim.x + threadIdx.x;
    if (e < NE_) atomicAdd(&g_deg[dst[e]], 1);
}

__global__ void k_scan1() {
    __shared__ int sd[256];
    int b = blockIdx.x, t = threadIdx.x, i = b * 256 + t;
    int v = (i < NN_) ? g_deg[i] : 0;
    sd[t] = v;
    __syncthreads();
    for (int off = 1; off < 256; off <<= 1) {
        int tv = (t >= off) ? sd[t - off] : 0;
        __syncthreads();
        sd[t] += tv;
        __syncthreads();
    }
    if (i < NN_) g_rowstart[i] = sd[t] - v;   // block-local exclusive
    if (t == 255) g_bsum[b] = sd[255];
}

__global__ void k_scan2() {
    __shared__ int sd[256];
    int t = threadIdx.x;
    int v = (t < NBLK_SCAN) ? g_bsum[t] : 0;
    sd[t] = v;
    __syncthreads();
    for (int off = 1; off < 256; off <<= 1) {
        int tv = (t >= off) ? sd[t - off] : 0;
        __syncthreads();
        sd[t] += tv;
        __syncthreads();
    }
    if (t < NBLK_SCAN) g_boff[t] = sd[t] - v;
    if (t == 255) g_rowstart[NN_] = sd[255];
}

__global__ void k_scan3() {
    int i = blockIdx.x * blockDim.x + threadIdx.x;
    if (i < NN_) {
        int r = g_rowstart[i] + g_boff[i >> 8];
        g_rowstart[i] = r;
        g_cursor[i] = r;
    }
}

__global__ void k_scatter(const int* __restrict__ src, const int* __restrict__ dst,
                          const float* __restrict__ ea) {
    int e = blockIdx.x * blockDim.x + threadIdx.x;
    if (e < NE_) {
        int pos = atomicAdd(&g_cursor[dst[e]], 1);
        g_srccsr[pos] = src[e];
        g_eacsr[pos] = reinterpret_cast<const float4*>(ea)[e];
    }
}

// ---------------- layer-1 node transforms: xl1/xr1 = x@W + b (bf16 out) ----------
__global__ void k_xform1(const float* __restrict__ x,
                         const float* __restrict__ Wl, const float* __restrict__ bl,
                         const float* __restrict__ Wr, const float* __restrict__ br) {
    int n = blockIdx.x * 4 + (threadIdx.x >> 6);
    int lane = threadIdx.x & 63;
    if (n >= NN_) return;
    float x0 = x[2 * n], x1 = x[2 * n + 1];
    int c4 = lane * 4;
    float l0 = x0 * Wl[c4 + 0] + x1 * Wl[256 + c4 + 0] + bl[c4 + 0];
    float l1 = x0 * Wl[c4 + 1] + x1 * Wl[256 + c4 + 1] + bl[c4 + 1];
    float l2 = x0 * Wl[c4 + 2] + x1 * Wl[256 + c4 + 2] + bl[c4 + 2];
    float l3 = x0 * Wl[c4 + 3] + x1 * Wl[256 + c4 + 3] + bl[c4 + 3];
    float r0 = x0 * Wr[c4 + 0] + x1 * Wr[256 + c4 + 0] + br[c4 + 0];
    float r1 = x0 * Wr[c4 + 1] + x1 * Wr[256 + c4 + 1] + br[c4 + 1];
    float r2 = x0 * Wr[c4 + 2] + x1 * Wr[256 + c4 + 2] + br[c4 + 2];
    float r3 = x0 * Wr[c4 + 3] + x1 * Wr[256 + c4 + 3] + br[c4 + 3];
    *reinterpret_cast<uint2*>(g_xl1 + (size_t)n * 256 + c4) = make_uint2(pack2(l0, l1), pack2(l2, l3));
    *reinterpret_cast<uint2*>(g_xr1 + (size_t)n * 256 + c4) = make_uint2(pack2(r0, r1), pack2(r2, r3));
}

// ---------------- fused GATv2 layer: logits + softmax + aggregate ----------------
// One block (256 thr) per destination node. D = H*C = 256 always.
// Phase A stages each gathered xl row into LDS; phase C reads LDS (no 2nd gather).
template <int LAYER>
__global__ void k_gat(const float* __restrict__ att, const float* __restrict__ We,
                      const float* __restrict__ bias) {
    constexpr int H = (LAYER == 1) ? 4 : 2;
    constexpr int C = (LAYER == 1) ? 64 : 128;
    constexpr bool CONCAT = (LAYER == 1);
    constexpr int GL = C / 4;           // lanes per head group in phase A
    const ushort_t* __restrict__ xl = (LAYER == 1) ? g_xl1 : g_xl2;
    const ushort_t* __restrict__ xr = (LAYER == 1) ? g_xr1 : g_xr2;
    float* __restrict__ hout = (LAYER == 1) ? g_h1 : g_h2;

    __shared__ uint2  srow[CH_][64];    // staged xl rows, packed bf16 (512B/row)
    __shared__ float slog[H][CH_];
    __shared__ float sw[H][CH_];
    __shared__ float sscale[H], sinv[H];
    __shared__ float stmp[256];

    int n = blockIdx.x;
    int tid = threadIdx.x;
    int wv = tid >> 6, lane = tid & 63;
    int h = tid / C;
    int c4 = lane * 4;

    // per-lane constants (scalar loads; no alignment assumptions on params)
    float a0 = att[c4], a1 = att[c4 + 1], a2c = att[c4 + 2], a3 = att[c4 + 3];
    float we00 = We[c4], we01 = We[c4 + 1], we02 = We[c4 + 2], we03 = We[c4 + 3];
    float we10 = We[256 + c4], we11 = We[256 + c4 + 1], we12 = We[256 + c4 + 2], we13 = We[256 + c4 + 3];
    float we20 = We[512 + c4], we21 = We[512 + c4 + 1], we22 = We[512 + c4 + 2], we23 = We[512 + c4 + 3];
    float we30 = We[768 + c4], we31 = We[768 + c4 + 1], we32 = We[768 + c4 + 2], we33 = We[768 + c4 + 3];
    uint2 xq = *reinterpret_cast<const uint2*>(xr + (size_t)n * 256 + c4);
    float xr0 = bflo(xq.x), xr1 = bfhi(xq.x), xr2 = bflo(xq.y), xr3 = bfhi(xq.y);

    int s0 = g_rowstart[n];
    int dtot = g_rowstart[n + 1] - s0;

    float mrun = -INFINITY, den = 0.f;   // live in wave-h lanes (wv < H)
    float acc = 0.f;                      // per-thread channel accumulator

    for (int c0 = 0; c0 < dtot; c0 += CH_) {
        int dc = min(CH_, dtot - c0);
        // ---- phase A: edge-per-wave logits + LDS row staging ----
        for (int i = wv; i < dc; i += 4) {
            int s = g_srccsr[s0 + c0 + i];
            float4 ea4 = g_eacsr[s0 + c0 + i];
            uint2 xlq = *reinterpret_cast<const uint2*>(xl + (size_t)s * 256 + c4);
            srow[i][lane] = xlq;
            float z0 = bflo(xlq.x) + xr0 + ea4.x * we00 + ea4.y * we10 + ea4.z * we20 + ea4.w * we30;
            float z1 = bfhi(xlq.x) + xr1 + ea4.x * we01 + ea4.y * we11 + ea4.z * we21 + ea4.w * we31;
            float z2 = bflo(xlq.y) + xr2 + ea4.x * we02 + ea4.y * we12 + ea4.z * we22 + ea4.w * we32;
            float z3 = bfhi(xlq.y) + xr3 + ea4.x * we03 + ea4.y * we13 + ea4.z * we23 + ea4.w * we33;
            z0 = fmaxf(z0, 0.2f * z0); z1 = fmaxf(z1, 0.2f * z1);
            z2 = fmaxf(z2, 0.2f * z2); z3 = fmaxf(z3, 0.2f * z3);
            float t = z0 * a0 + z1 * a1 + z2 * a2c + z3 * a3;
#pragma unroll
            for (int off = 1; off < GL; off <<= 1) t += __shfl_xor(t, off);
            if ((lane & (GL - 1)) == 0) slog[lane / GL][i] = t;
        }
        __syncthreads();
        // ---- phase B: online softmax (wave per head) ----
        if (wv < H) {
            float mc = -INFINITY;
            for (int i = lane; i < dc; i += 64) mc = fmaxf(mc, slog[wv][i]);
#pragma unroll
            for (int off = 1; off < 64; off <<= 1) mc = fmaxf(mc, __shfl_xor(mc, off));
            float mnew = fmaxf(mrun, mc);
            float sc = expf(mrun - mnew);
            float dl = 0.f;
            for (int i = lane; i < dc; i += 64) {
                float w = expf(slog[wv][i] - mnew);
                sw[wv][i] = w;
                dl += w;
            }
#pragma unroll
            for (int off = 1; off < 64; off <<= 1) dl += __shfl_xor(dl, off);
            den = den * sc + dl;
            mrun = mnew;
            if (lane == 0) sscale[wv] = sc;
        }
        __syncthreads();
        // ---- phase C: weighted aggregate from LDS-staged rows ----
        float scl = sscale[h];
        float a2 = 0.f;
        const ushort_t* srow_flat = reinterpret_cast<const ushort_t*>(srow);
        for (int i = 0; i < dc; ++i)
            a2 = fmaf(sw[h][i], bf2f(srow_flat[i * 256 + tid]), a2);
        acc = acc * scl + a2;
        __syncthreads();
    }
    if (wv < H && lane == 0) sinv[wv] = 1.f / (den + 1e-16f);
    __syncthreads();
    float outv = acc * sinv[h];
    if (CONCAT) {
        hout[(size_t)n * 256 + tid] = outv + bias[tid];
    } else {
        stmp[tid] = outv;
        __syncthreads();
        if (tid < C) hout[(size_t)n * C + tid] = 0.5f * (stmp[tid] + stmp[tid + C]) + bias[tid];
    }
}

// ---------------- batchnorm ----------------
template <int C>
__global__ void k_bn_stats() {
    const float* h = (C == 256) ? (const float*)g_h1 : (const float*)g_h2;
    int c = threadIdx.x;
    int r0 = blockIdx.x * 100;
    float s = 0.f, ss = 0.f;
    for (int r = 0; r < 100; ++r) {
        float v = h[(size_t)(r0 + r) * C + c];
        s += v; ss += v * v;
    }
    atomicAdd(&g_sum[c], s);
    atomicAdd(&g_sq[c], ss);
}

template <int C>
__global__ void k_bn_finalize(const float* __restrict__ g, const float* __restrict__ b) {
    int c = threadIdx.x;
    float mu = g_sum[c] / (float)NN_;
    float var = g_sq[c] / (float)NN_ - mu * mu;
    float sc = g[c] * rsqrtf(var + 1e-5f);
    g_scale[c] = sc;
    g_shift[c] = b[c] - mu * sc;
    g_sum[c] = 0.f; g_sq[c] = 0.f;
}

template <int C>
__global__ void k_bn_apply() {
    float* h = (C == 256) ? (float*)g_h1 : (float*)g_h2;
    int i = blockIdx.x * blockDim.x + threadIdx.x;
    int stride = gridDim.x * blockDim.x;
    for (int j = i; j < NN_ * C; j += stride) {
        int c = j & (C - 1);
        float v = h[j] * g_scale[c] + g_shift[c];
        h[j] = v > 0.f ? v : expm1f(v);
    }
}

// ---------------- dual SGEMM: g_h1 @ {Wl2, Wr2} + bias -> g_xl2/g_xr2 (bf16) ------
// A tile staged once, multiplied by both weight matrices.
__global__ void k_gemm2(const float* __restrict__ Wl, const float* __restrict__ bl,
                        const float* __restrict__ Wr, const float* __restrict__ br) {
    const float* A = g_h1;
    const int K = 256, NNc = 256;
    __shared__ float As[32][65];
    __shared__ float Bs[2][32][64];
    int tid = threadIdx.x;
    int tx = tid & 15, ty = tid >> 4;
    int m0 = blockIdx.x * 64, n0 = blockIdx.y * 64;
    int la_r = tid >> 2;            // 0..63 row (m)
    int la_c = (tid & 3) * 8;       // k offset
    int lb_r = tid >> 3;            // 0..31 (k)
    int lb_c = (tid & 7) * 8;       // n offset
    float accl[4][4] = {}, accr[4][4] = {};
    for (int k0 = 0; k0 < K; k0 += 32) {
        const float4* Ap = reinterpret_cast<const float4*>(A + (size_t)(m0 + la_r) * K + k0 + la_c);
        float4 a0 = Ap[0], a1 = Ap[1];
        As[la_c + 0][la_r] = a0.x; As[la_c + 1][la_r] = a0.y;
        As[la_c + 2][la_r] = a0.z; As[la_c + 3][la_r] = a0.w;
        As[la_c + 4][la_r] = a1.x; As[la_c + 5][la_r] = a1.y;
        As[la_c + 6][la_r] = a1.z; As[la_c + 7][la_r] = a1.w;
        const float4* Wpl = reinterpret_cast<const float4*>(Wl + (size_t)(k0 + lb_r) * NNc + n0 + lb_c);
        *reinterpret_cast<float4*>(&Bs[0][lb_r][lb_c]) = Wpl[0];
        *reinterpret_cast<float4*>(&Bs[0][lb_r][lb_c + 4]) = Wpl[1];
        const float4* Wpr = reinterpret_cast<const float4*>(Wr + (size_t)(k0 + lb_r) * NNc + n0 + lb_c);
        *reinterpret_cast<float4*>(&Bs[1][lb_r][lb_c]) = Wpr[0];
        *reinterpret_cast<float4*>(&Bs[1][lb_r][lb_c + 4]) = Wpr[1];
        __syncthreads();
#pragma unroll
        for (int k = 0; k < 32; ++k) {
            float a[4], b0[4], b1[4];
#pragma unroll
            for (int i = 0; i < 4; ++i) a[i] = As[k][ty * 4 + i];
#pragma unroll
            for (int j = 0; j < 4; ++j) { b0[j] = Bs[0][k][tx * 4 + j]; b1[j] = Bs[1][k][tx * 4 + j]; }
#pragma unroll
            for (int i = 0; i < 4; ++i)
#pragma unroll
                for (int j = 0; j < 4; ++j) {
                    accl[i][j] = fmaf(a[i], b0[j], accl[i][j]);
                    accr[i][j] = fmaf(a[i], b1[j], accr[i][j]);
                }
        }
        __syncthreads();
    }
    float bl0 = bl[n0 + tx * 4 + 0], bl1 = bl[n0 + tx * 4 + 1];
    float bl2v = bl[n0 + tx * 4 + 2], bl3 = bl[n0 + tx * 4 + 3];
    float br0 = br[n0 + tx * 4 + 0], br1 = br[n0 + tx * 4 + 1];
    float br2v = br[n0 + tx * 4 + 2], br3 = br[n0 + tx * 4 + 3];
#pragma unroll
    for (int i = 0; i < 4; ++i) {
        int m = m0 + ty * 4 + i;
        uint2 ul = make_uint2(pack2(accl[i][0] + bl0, accl[i][1] + bl1),
                              pack2(accl[i][2] + bl2v, accl[i][3] + bl3));
        uint2 ur = make_uint2(pack2(accr[i][0] + br0, accr[i][1] + br1),
                              pack2(accr[i][2] + br2v, accr[i][3] + br3));
        *reinterpret_cast<uint2*>(g_xl2 + (size_t)m * NNc + n0 + tx * 4) = ul;
        *reinterpret_cast<uint2*>(g_xr2 + (size_t)m * NNc + n0 + tx * 4) = ur;
    }
}

// ---------------- global mean pool (batch is sorted -> block per graph) ----------
__global__ void k_pool2(const int* __restrict__ batch) {
    int g = blockIdx.x, t = threadIdx.x;  // 128 threads
    __shared__ int sbeg, send;
    if (t == 0) {
        int lo = 0, hi = NN_;
        while (lo < hi) { int mid = (lo + hi) >> 1; if (batch[mid] < g) lo = mid + 1; else hi = mid; }
        sbeg = lo;
    }
    if (t == 1) {
        int lo = 0, hi = NN_;
        while (lo < hi) { int mid = (lo + hi) >> 1; if (batch[mid] <= g) lo = mid + 1; else hi = mid; }
        send = lo;
    }
    __syncthreads();
    int beg = sbeg, end = send;
    float acc = 0.f;
    for (int n = beg; n < end; ++n) acc += g_h2[(size_t)n * 128 + t];
    g_pool[g * 128 + t] = acc;
    if (t == 0) g_count[g] = end - beg;
}

// ---------------- MLP head ----------------
__global__ void k_head(const float* __restrict__ W1, const float* __restrict__ b1,
                       const float* __restrict__ W2, const float* __restrict__ b2,
                       float* __restrict__ out) {
    int g = blockIdx.x, t = threadIdx.x;  // 64 threads
    __shared__ float p[128], hm[64];
    float cnt = fmaxf((float)g_count[g], 1.f);
    float inv = 1.f / cnt;
    p[t] = g_pool[g * 128 + t] * inv;
    p[t + 64] = g_pool[g * 128 + 64 + t] * inv;
    __syncthreads();
    float a = b1[t];
    for (int k = 0; k < 128; ++k) a += p[k] * W1[k * 64 + t];
    hm[t] = a > 0.f ? a : expm1f(a);
    __syncthreads();
    if (t < 12) {
        float o = b2[t];
        for (int k = 0; k < 64; ++k) o += hm[k] * W2[k * 12 + t];
        out[g * 12 + t] = o;
    }
}

// ---------------- launch ----------------
extern "C" void kernel_launch(void* const* d_in, const int* in_sizes, int n_in,
                              void* d_out, int out_size, void* d_ws, size_t ws_size,
                              hipStream_t stream) {
    const float* x     = (const float*)d_in[0];
    const int*   ei    = (const int*)d_in[1];
    const float* ea    = (const float*)d_in[2];
    const int*   batch = (const int*)d_in[3];
    const float* Wl1   = (const float*)d_in[4];
    const float* bl1   = (const float*)d_in[5];
    const float* Wr1   = (const float*)d_in[6];
    const float* br1   = (const float*)d_in[7];
    const float* We1   = (const float*)d_in[8];
    const float* att1  = (const float*)d_in[9];
    const float* bias1 = (const float*)d_in[10];
    const float* g1    = (const float*)d_in[11];
    const float* be1   = (const float*)d_in[12];
    const float* Wl2   = (const float*)d_in[13];
    const float* bl2   = (const float*)d_in[14];
    const float* Wr2   = (const float*)d_in[15];
    const float* br2   = (const float*)d_in[16];
    const float* We2   = (const float*)d_in[17];
    const float* att2  = (const float*)d_in[18];
    const float* bias2 = (const float*)d_in[19];
    const float* g2    = (const float*)d_in[20];
    const float* be2   = (const float*)d_in[21];
    const float* Wlin1 = (const float*)d_in[22];
    const float* blin1 = (const float*)d_in[23];
    const float* Wlin2 = (const float*)d_in[24];
    const float* blin2 = (const float*)d_in[25];
    float* out = (float*)d_out;
    const int* src = ei;
    const int* dst = ei + NE_;

    k_zero<<<256, 256, 0, stream>>>();
    k_hist<<<2500, 256, 0, stream>>>(dst);
    k_scan1<<<NBLK_SCAN, 256, 0, stream>>>();
    k_scan2<<<1, 256, 0, stream>>>();
    k_scan3<<<NBLK_SCAN, 256, 0, stream>>>();
    k_scatter<<<2500, 256, 0, stream>>>(src, dst, ea);

    // layer 1
    k_xform1<<<10000, 256, 0, stream>>>(x, Wl1, bl1, Wr1, br1);
    k_gat<1><<<NN_, 256, 0, stream>>>(att1, We1, bias1);
    k_bn_stats<256><<<400, 256, 0, stream>>>();
    k_bn_finalize<256><<<1, 256, 0, stream>>>(g1, be1);
    k_bn_apply<256><<<4096, 256, 0, stream>>>();

    // layer 2 projections (fp32 in, bf16 out, fused dual-GEMM)
    k_gemm2<<<dim3(625, 4), 256, 0, stream>>>(Wl2, bl2, Wr2, br2);

    // layer 2
    k_gat<2><<<NN_, 256, 0, stream>>>(att2, We2, bias2);
    k_bn_stats<128><<<400, 128, 0, stream>>>();
    k_bn_finalize<128><<<1, 128, 0, stream>>>(g2, be2);
    k_bn_apply<128><<<4096, 256, 0, stream>>>();

    // pool + head
    k_pool2<<<NG_, 128, 0, stream>>>(batch);
    k_head<<<NG_, 64, 0, stream>>>(Wlin1, blin1, Wlin2, blin2, out);
}

// Round 7
// 582.900 us; speedup vs baseline: 2.6791x; 1.1587x over previous
//
#include <hip/hip_runtime.h>
#include <math.h>

#define NN_ 40000
#define NE_ 640000
#define NG_ 400
#define NBLK_SCAN 157    // ceil(40000/256)

typedef unsigned short ushort_t;

// ---------------- device scratch ----------------
// NOTE: __device__ globals must NEVER be passed as kernel arguments from host
// (host sees shadow symbol address -> GPU fault). Always bind inside kernels.
__device__ int    g_deg[NN_];
__device__ int    g_rowstart[NN_ + 1];
__device__ int    g_cursor[NN_];
__device__ int    g_srccsr[NE_];
__device__ float4 g_eacsr[NE_];
__device__ int    g_bsum[NBLK_SCAN], g_boff[NBLK_SCAN];
__device__ ushort_t g_xl1[(size_t)NN_ * 256];
__device__ ushort_t g_xr1[(size_t)NN_ * 256];
__device__ ushort_t g_xl2[(size_t)NN_ * 256];
__device__ ushort_t g_xr2[(size_t)NN_ * 256];
__device__ float  g_h1[(size_t)NN_ * 256];
__device__ float  g_h2[(size_t)NN_ * 128];
__device__ float  g_sum[256], g_sq[256];
__device__ float  g_scale[256], g_shift[256];
__device__ float  g_pool[NG_ * 128];
__device__ int    g_count[NG_];

// bf16 helpers: arrays of ushort bf16, accessed pairwise via uint
__device__ __forceinline__ float bflo(unsigned int q) { return __uint_as_float(q << 16); }
__device__ __forceinline__ float bfhi(unsigned int q) { return __uint_as_float(q & 0xFFFF0000u); }
__device__ __forceinline__ unsigned int f2bf(float f) {
    unsigned int u = __float_as_uint(f);
    return (u + 0x7FFFu + ((u >> 16) & 1u)) >> 16;
}
__device__ __forceinline__ unsigned int pack2(float a, float b) {
    return f2bf(a) | (f2bf(b) << 16);
}

// ---------------- init ----------------
__global__ void k_zero() {
    int i = blockIdx.x * blockDim.x + threadIdx.x;
    int stride = gridDim.x * blockDim.x;
    for (int j = i; j < NN_; j += stride) g_deg[j] = 0;
    for (int j = i; j < 256; j += stride) { g_sum[j] = 0.f; g_sq[j] = 0.f; }
}

// ---------------- CSR build ----------------
__global__ void k_hist(const int* __restrict__ dst) {
    int e = blockIdx.x * blockDim.x + threadIdx.x;
    if (e < NE_) atomicAdd(&g_deg[dst[e]], 1);
}

__global__ void k_scan1() {
    __shared__ int sd[256];
    int b = blockIdx.x, t = threadIdx.x, i = b * 256 + t;
    int v = (i < NN_) ? g_deg[i] : 0;
    sd[t] = v;
    __syncthreads();
    for (int off = 1; off < 256; off <<= 1) {
        int tv = (t >= off) ? sd[t - off] : 0;
        __syncthreads();
        sd[t] += tv;
        __syncthreads();
    }
    if (i < NN_) g_rowstart[i] = sd[t] - v;   // block-local exclusive
    if (t == 255) g_bsum[b] = sd[255];
}

__global__ void k_scan2() {
    __shared__ int sd[256];
    int t = threadIdx.x;
    int v = (t < NBLK_SCAN) ? g_bsum[t] : 0;
    sd[t] = v;
    __syncthreads();
    for (int off = 1; off < 256; off <<= 1) {
        int tv = (t >= off) ? sd[t - off] : 0;
        __syncthreads();
        sd[t] += tv;
        __syncthreads();
    }
    if (t < NBLK_SCAN) g_boff[t] = sd[t] - v;
    if (t == 255) g_rowstart[NN_] = sd[255];
}

__global__ void k_scan3() {
    int i = blockIdx.x * blockDim.x + threadIdx.x;
    if (i < NN_) {
        int r = g_rowstart[i] + g_boff[i >> 8];
        g_rowstart[i] = r;
        g_cursor[i] = r;
    }
}

__global__ void k_scatter(const int* __restrict__ src, const int* __restrict__ dst,
                          const float* __restrict__ ea) {
    int e = blockIdx.x * blockDim.x + threadIdx.x;
    if (e < NE_) {
        int pos = atomicAdd(&g_cursor[dst[e]], 1);
        g_srccsr[pos] = src[e];
        g_eacsr[pos] = reinterpret_cast<const float4*>(ea)[e];
    }
}

// ---------------- layer-1 node transforms: xl1/xr1 = x@W + b (bf16 out) ----------
__global__ void k_xform1(const float* __restrict__ x,
                         const float* __restrict__ Wl, const float* __restrict__ bl,
                         const float* __restrict__ Wr, const float* __restrict__ br) {
    int n = blockIdx.x * 4 + (threadIdx.x >> 6);
    int lane = threadIdx.x & 63;
    if (n >= NN_) return;
    float x0 = x[2 * n], x1 = x[2 * n + 1];
    int c4 = lane * 4;
    float l0 = x0 * Wl[c4 + 0] + x1 * Wl[256 + c4 + 0] + bl[c4 + 0];
    float l1 = x0 * Wl[c4 + 1] + x1 * Wl[256 + c4 + 1] + bl[c4 + 1];
    float l2 = x0 * Wl[c4 + 2] + x1 * Wl[256 + c4 + 2] + bl[c4 + 2];
    float l3 = x0 * Wl[c4 + 3] + x1 * Wl[256 + c4 + 3] + bl[c4 + 3];
    float r0 = x0 * Wr[c4 + 0] + x1 * Wr[256 + c4 + 0] + br[c4 + 0];
    float r1 = x0 * Wr[c4 + 1] + x1 * Wr[256 + c4 + 1] + br[c4 + 1];
    float r2 = x0 * Wr[c4 + 2] + x1 * Wr[256 + c4 + 2] + br[c4 + 2];
    float r3 = x0 * Wr[c4 + 3] + x1 * Wr[256 + c4 + 3] + br[c4 + 3];
    *reinterpret_cast<uint2*>(g_xl1 + (size_t)n * 256 + c4) = make_uint2(pack2(l0, l1), pack2(l2, l3));
    *reinterpret_cast<uint2*>(g_xr1 + (size_t)n * 256 + c4) = make_uint2(pack2(r0, r1), pack2(r2, r3));
}

// ---------------- fused GATv2 layer: flash-style, wave per node ----------------
// One 64-lane wave owns one destination node; lane owns channels c4=lane*4..+3.
// Per edge: one row gather (in-register reuse for aggregate), head-group shuffle
// reduce for the logit, online-softmax rescale of acc/den. No LDS, no barriers.
template <int LAYER>
__global__ void k_gat(const float* __restrict__ att, const float* __restrict__ We,
                      const float* __restrict__ bias) {
    constexpr int C = (LAYER == 1) ? 64 : 128;    // channels per head
    constexpr int GL = C / 4;                     // lanes per head group
    const ushort_t* __restrict__ xl = (LAYER == 1) ? g_xl1 : g_xl2;
    const ushort_t* __restrict__ xr = (LAYER == 1) ? g_xr1 : g_xr2;
    float* __restrict__ hout = (LAYER == 1) ? g_h1 : g_h2;

    int wv = threadIdx.x >> 6, lane = threadIdx.x & 63;
    int n = blockIdx.x * 4 + wv;
    if (n >= NN_) return;
    int c4 = lane * 4;

    // per-lane constants (scalar loads; no alignment assumptions on params)
    float a0 = att[c4], a1 = att[c4 + 1], a2c = att[c4 + 2], a3 = att[c4 + 3];
    float we00 = We[c4], we01 = We[c4 + 1], we02 = We[c4 + 2], we03 = We[c4 + 3];
    float we10 = We[256 + c4], we11 = We[256 + c4 + 1], we12 = We[256 + c4 + 2], we13 = We[256 + c4 + 3];
    float we20 = We[512 + c4], we21 = We[512 + c4 + 1], we22 = We[512 + c4 + 2], we23 = We[512 + c4 + 3];
    float we30 = We[768 + c4], we31 = We[768 + c4 + 1], we32 = We[768 + c4 + 2], we33 = We[768 + c4 + 3];
    uint2 xq = *reinterpret_cast<const uint2*>(xr + (size_t)n * 256 + c4);
    float xr0 = bflo(xq.x), xr1 = bfhi(xq.x), xr2 = bflo(xq.y), xr3 = bfhi(xq.y);

    int s0 = g_rowstart[n];
    int d = g_rowstart[n + 1] - s0;

    float mrun = -INFINITY, den = 0.f;
    float acc0 = 0.f, acc1 = 0.f, acc2 = 0.f, acc3 = 0.f;

    // software pipeline: prefetch edge i+1 (index, edge-attr, xl row) during edge i
    int   sA = 0;
    float4 eaA = make_float4(0.f, 0.f, 0.f, 0.f);
    uint2 rowA = make_uint2(0u, 0u);
    if (d > 0) {
        sA = g_srccsr[s0];
        eaA = g_eacsr[s0];
        rowA = *reinterpret_cast<const uint2*>(xl + (size_t)sA * 256 + c4);
    }
    for (int i = 0; i < d; ++i) {
        int   sB = sA;
        float4 eaB = eaA;
        uint2 rowB = rowA;
        if (i + 1 < d) {
            sB = g_srccsr[s0 + i + 1];
            eaB = g_eacsr[s0 + i + 1];
            rowB = *reinterpret_cast<const uint2*>(xl + (size_t)sB * 256 + c4);
        }
        float xl0 = bflo(rowA.x), xl1 = bfhi(rowA.x), xl2 = bflo(rowA.y), xl3 = bfhi(rowA.y);
        float z0 = xl0 + xr0 + eaA.x * we00 + eaA.y * we10 + eaA.z * we20 + eaA.w * we30;
        float z1 = xl1 + xr1 + eaA.x * we01 + eaA.y * we11 + eaA.z * we21 + eaA.w * we31;
        float z2 = xl2 + xr2 + eaA.x * we02 + eaA.y * we12 + eaA.z * we22 + eaA.w * we32;
        float z3 = xl3 + xr3 + eaA.x * we03 + eaA.y * we13 + eaA.z * we23 + eaA.w * we33;
        z0 = fmaxf(z0, 0.2f * z0); z1 = fmaxf(z1, 0.2f * z1);
        z2 = fmaxf(z2, 0.2f * z2); z3 = fmaxf(z3, 0.2f * z3);
        float t = z0 * a0 + z1 * a1 + z2 * a2c + z3 * a3;
#pragma unroll
        for (int off = 1; off < GL; off <<= 1) t += __shfl_xor(t, off);
        // online softmax update (per lane, uniform within head group)
        float mnew = fmaxf(mrun, t);
        float scl = __expf(mrun - mnew);
        float w = __expf(t - mnew);
        den = den * scl + w;
        acc0 = acc0 * scl + w * xl0;
        acc1 = acc1 * scl + w * xl1;
        acc2 = acc2 * scl + w * xl2;
        acc3 = acc3 * scl + w * xl3;
        mrun = mnew;
        sA = sB; eaA = eaB; rowA = rowB;
    }
    float inv = 1.f / (den + 1e-16f);
    if (LAYER == 1) {
        float4 o = make_float4(acc0 * inv + bias[c4 + 0], acc1 * inv + bias[c4 + 1],
                               acc2 * inv + bias[c4 + 2], acc3 * inv + bias[c4 + 3]);
        *reinterpret_cast<float4*>(hout + (size_t)n * 256 + c4) = o;
    } else {
        // mean over 2 heads: lane l (head0, ch c4) pairs with lane l+32 (head1, ch c4)
        float v0 = acc0 * inv, v1 = acc1 * inv, v2 = acc2 * inv, v3 = acc3 * inv;
        float u0 = __shfl_xor(v0, 32), u1 = __shfl_xor(v1, 32);
        float u2 = __shfl_xor(v2, 32), u3 = __shfl_xor(v3, 32);
        if (lane < 32) {
            float4 o = make_float4(0.5f * (v0 + u0) + bias[c4 + 0],
                                   0.5f * (v1 + u1) + bias[c4 + 1],
                                   0.5f * (v2 + u2) + bias[c4 + 2],
                                   0.5f * (v3 + u3) + bias[c4 + 3]);
            *reinterpret_cast<float4*>(hout + (size_t)n * 128 + c4) = o;
        }
    }
}

// ---------------- batchnorm ----------------
template <int C>
__global__ void k_bn_stats() {
    const float* h = (C == 256) ? (const float*)g_h1 : (const float*)g_h2;
    int c = threadIdx.x;
    int r0 = blockIdx.x * 100;
    float s = 0.f, ss = 0.f;
    for (int r = 0; r < 100; ++r) {
        float v = h[(size_t)(r0 + r) * C + c];
        s += v; ss += v * v;
    }
    atomicAdd(&g_sum[c], s);
    atomicAdd(&g_sq[c], ss);
}

template <int C>
__global__ void k_bn_finalize(const float* __restrict__ g, const float* __restrict__ b) {
    int c = threadIdx.x;
    float mu = g_sum[c] / (float)NN_;
    float var = g_sq[c] / (float)NN_ - mu * mu;
    float sc = g[c] * rsqrtf(var + 1e-5f);
    g_scale[c] = sc;
    g_shift[c] = b[c] - mu * sc;
    g_sum[c] = 0.f; g_sq[c] = 0.f;
}

template <int C>
__global__ void k_bn_apply() {
    float* h = (C == 256) ? (float*)g_h1 : (float*)g_h2;
    int i = blockIdx.x * blockDim.x + threadIdx.x;
    int stride = gridDim.x * blockDim.x;
    for (int j = i; j < NN_ * C; j += stride) {
        int c = j & (C - 1);
        float v = h[j] * g_scale[c] + g_shift[c];
        h[j] = v > 0.f ? v : expm1f(v);
    }
}

// ---------------- dual SGEMM: g_h1 @ {Wl2, Wr2} + bias -> g_xl2/g_xr2 (bf16) ------
// A tile staged once, multiplied by both weight matrices.
__global__ void k_gemm2(const float* __restrict__ Wl, const float* __restrict__ bl,
                        const float* __restrict__ Wr, const float* __restrict__ br) {
    const float* A = g_h1;
    const int K = 256, NNc = 256;
    __shared__ float As[32][65];
    __shared__ float Bs[2][32][64];
    int tid = threadIdx.x;
    int tx = tid & 15, ty = tid >> 4;
    int m0 = blockIdx.x * 64, n0 = blockIdx.y * 64;
    int la_r = tid >> 2;            // 0..63 row (m)
    int la_c = (tid & 3) * 8;       // k offset
    int lb_r = tid >> 3;            // 0..31 (k)
    int lb_c = (tid & 7) * 8;       // n offset
    float accl[4][4] = {}, accr[4][4] = {};
    for (int k0 = 0; k0 < K; k0 += 32) {
        const float4* Ap = reinterpret_cast<const float4*>(A + (size_t)(m0 + la_r) * K + k0 + la_c);
        float4 a0 = Ap[0], a1 = Ap[1];
        As[la_c + 0][la_r] = a0.x; As[la_c + 1][la_r] = a0.y;
        As[la_c + 2][la_r] = a0.z; As[la_c + 3][la_r] = a0.w;
        As[la_c + 4][la_r] = a1.x; As[la_c + 5][la_r] = a1.y;
        As[la_c + 6][la_r] = a1.z; As[la_c + 7][la_r] = a1.w;
        const float4* Wpl = reinterpret_cast<const float4*>(Wl + (size_t)(k0 + lb_r) * NNc + n0 + lb_c);
        *reinterpret_cast<float4*>(&Bs[0][lb_r][lb_c]) = Wpl[0];
        *reinterpret_cast<float4*>(&Bs[0][lb_r][lb_c + 4]) = Wpl[1];
        const float4* Wpr = reinterpret_cast<const float4*>(Wr + (size_t)(k0 + lb_r) * NNc + n0 + lb_c);
        *reinterpret_cast<float4*>(&Bs[1][lb_r][lb_c]) = Wpr[0];
        *reinterpret_cast<float4*>(&Bs[1][lb_r][lb_c + 4]) = Wpr[1];
        __syncthreads();
#pragma unroll
        for (int k = 0; k < 32; ++k) {
            float a[4], b0[4], b1[4];
#pragma unroll
            for (int i = 0; i < 4; ++i) a[i] = As[k][ty * 4 + i];
#pragma unroll
            for (int j = 0; j < 4; ++j) { b0[j] = Bs[0][k][tx * 4 + j]; b1[j] = Bs[1][k][tx * 4 + j]; }
#pragma unroll
            for (int i = 0; i < 4; ++i)
#pragma unroll
                for (int j = 0; j < 4; ++j) {
                    accl[i][j] = fmaf(a[i], b0[j], accl[i][j]);
                    accr[i][j] = fmaf(a[i], b1[j], accr[i][j]);
                }
        }
        __syncthreads();
    }
    float bl0 = bl[n0 + tx * 4 + 0], bl1 = bl[n0 + tx * 4 + 1];
    float bl2v = bl[n0 + tx * 4 + 2], bl3 = bl[n0 + tx * 4 + 3];
    float br0 = br[n0 + tx * 4 + 0], br1 = br[n0 + tx * 4 + 1];
    float br2v = br[n0 + tx * 4 + 2], br3 = br[n0 + tx * 4 + 3];
#pragma unroll
    for (int i = 0; i < 4; ++i) {
        int m = m0 + ty * 4 + i;
        uint2 ul = make_uint2(pack2(accl[i][0] + bl0, accl[i][1] + bl1),
                              pack2(accl[i][2] + bl2v, accl[i][3] + bl3));
        uint2 ur = make_uint2(pack2(accr[i][0] + br0, accr[i][1] + br1),
                              pack2(accr[i][2] + br2v, accr[i][3] + br3));
        *reinterpret_cast<uint2*>(g_xl2 + (size_t)m * NNc + n0 + tx * 4) = ul;
        *reinterpret_cast<uint2*>(g_xr2 + (size_t)m * NNc + n0 + tx * 4) = ur;
    }
}

// ---------------- global mean pool (batch is sorted -> block per graph) ----------
__global__ void k_pool2(const int* __restrict__ batch) {
    int g = blockIdx.x, t = threadIdx.x;  // 128 threads
    __shared__ int sbeg, send;
    if (t == 0) {
        int lo = 0, hi = NN_;
        while (lo < hi) { int mid = (lo + hi) >> 1; if (batch[mid] < g) lo = mid + 1; else hi = mid; }
        sbeg = lo;
    }
    if (t == 1) {
        int lo = 0, hi = NN_;
        while (lo < hi) { int mid = (lo + hi) >> 1; if (batch[mid] <= g) lo = mid + 1; else hi = mid; }
        send = lo;
    }
    __syncthreads();
    int beg = sbeg, end = send;
    float acc = 0.f;
    for (int n = beg; n < end; ++n) acc += g_h2[(size_t)n * 128 + t];
    g_pool[g * 128 + t] = acc;
    if (t == 0) g_count[g] = end - beg;
}

// ---------------- MLP head ----------------
__global__ void k_head(const float* __restrict__ W1, const float* __restrict__ b1,
                       const float* __restrict__ W2, const float* __restrict__ b2,
                       float* __restrict__ out) {
    int g = blockIdx.x, t = threadIdx.x;  // 64 threads
    __shared__ float p[128], hm[64];
    float cnt = fmaxf((float)g_count[g], 1.f);
    float inv = 1.f / cnt;
    p[t] = g_pool[g * 128 + t] * inv;
    p[t + 64] = g_pool[g * 128 + 64 + t] * inv;
    __syncthreads();
    float a = b1[t];
    for (int k = 0; k < 128; ++k) a += p[k] * W1[k * 64 + t];
    hm[t] = a > 0.f ? a : expm1f(a);
    __syncthreads();
    if (t < 12) {
        float o = b2[t];
        for (int k = 0; k < 64; ++k) o += hm[k] * W2[k * 12 + t];
        out[g * 12 + t] = o;
    }
}

// ---------------- launch ----------------
extern "C" void kernel_launch(void* const* d_in, const int* in_sizes, int n_in,
                              void* d_out, int out_size, void* d_ws, size_t ws_size,
                              hipStream_t stream) {
    const float* x     = (const float*)d_in[0];
    const int*   ei    = (const int*)d_in[1];
    const float* ea    = (const float*)d_in[2];
    const int*   batch = (const int*)d_in[3];
    const float* Wl1   = (const float*)d_in[4];
    const float* bl1   = (const float*)d_in[5];
    const float* Wr1   = (const float*)d_in[6];
    const float* br1   = (const float*)d_in[7];
    const float* We1   = (const float*)d_in[8];
    const float* att1  = (const float*)d_in[9];
    const float* bias1 = (const float*)d_in[10];
    const float* g1    = (const float*)d_in[11];
    const float* be1   = (const float*)d_in[12];
    const float* Wl2   = (const float*)d_in[13];
    const float* bl2   = (const float*)d_in[14];
    const float* Wr2   = (const float*)d_in[15];
    const float* br2   = (const float*)d_in[16];
    const float* We2   = (const float*)d_in[17];
    const float* att2  = (const float*)d_in[18];
    const float* bias2 = (const float*)d_in[19];
    const float* g2    = (const float*)d_in[20];
    const float* be2   = (const float*)d_in[21];
    const float* Wlin1 = (const float*)d_in[22];
    const float* blin1 = (const float*)d_in[23];
    const float* Wlin2 = (const float*)d_in[24];
    const float* blin2 = (const float*)d_in[25];
    float* out = (float*)d_out;
    const int* src = ei;
    const int* dst = ei + NE_;

    k_zero<<<256, 256, 0, stream>>>();
    k_hist<<<2500, 256, 0, stream>>>(dst);
    k_scan1<<<NBLK_SCAN, 256, 0, stream>>>();
    k_scan2<<<1, 256, 0, stream>>>();
    k_scan3<<<NBLK_SCAN, 256, 0, stream>>>();
    k_scatter<<<2500, 256, 0, stream>>>(src, dst, ea);

    // layer 1
    k_xform1<<<10000, 256, 0, stream>>>(x, Wl1, bl1, Wr1, br1);
    k_gat<1><<<10000, 256, 0, stream>>>(att1, We1, bias1);
    k_bn_stats<256><<<400, 256, 0, stream>>>();
    k_bn_finalize<256><<<1, 256, 0, stream>>>(g1, be1);
    k_bn_apply<256><<<4096, 256, 0, stream>>>();

    // layer 2 projections (fp32 in, bf16 out, fused dual-GEMM)
    k_gemm2<<<dim3(625, 4), 256, 0, stream>>>(Wl2, bl2, Wr2, br2);

    // layer 2
    k_gat<2><<<10000, 256, 0, stream>>>(att2, We2, bias2);
    k_bn_stats<128><<<400, 128, 0, stream>>>();
    k_bn_finalize<128><<<1, 128, 0, stream>>>(g2, be2);
    k_bn_apply<128><<<4096, 256, 0, stream>>>();

    // pool + head
    k_pool2<<<NG_, 128, 0, stream>>>(batch);
    k_head<<<NG_, 64, 0, stream>>>(Wlin1, blin1, Wlin2, blin2, out);
}

// Round 9
// 478.451 us; speedup vs baseline: 3.2639x; 1.2183x over previous
//
#include <hip/hip_runtime.h>
#include <math.h>

#define NN_ 40000
#define NE_ 640000
#define NG_ 400
#define NBLK_SCAN 157    // ceil(40000/256)

typedef unsigned short ushort_t;
typedef __attribute__((ext_vector_type(8))) short bf16x8;
typedef __attribute__((ext_vector_type(4))) float f32x4;

// ---------------- device scratch ----------------
// NOTE: __device__ globals must NEVER be passed as kernel arguments from host
// (host sees shadow symbol address -> GPU fault). Always bind inside kernels.
__device__ int    g_deg[NN_];
__device__ int    g_rowstart[NN_ + 1];
__device__ int    g_cursor[NN_];
__device__ int    g_srccsr[NE_];
__device__ float4 g_eacsr[NE_];
__device__ int    g_bsum[NBLK_SCAN], g_boff[NBLK_SCAN];
__device__ ushort_t g_xl1[(size_t)NN_ * 256];
__device__ ushort_t g_xr1[(size_t)NN_ * 256];
__device__ ushort_t g_xl2[(size_t)NN_ * 256];
__device__ ushort_t g_xr2[(size_t)NN_ * 256];
__device__ float  g_h1[(size_t)NN_ * 256];
__device__ ushort_t g_h1b[(size_t)NN_ * 256];   // bf16 h1 (post BN+ELU) for MFMA GEMM
__device__ ushort_t g_wl2t[256 * 256];          // Wl2^T bf16 [n][k]
__device__ ushort_t g_wr2t[256 * 256];          // Wr2^T bf16 [n][k]
__device__ float  g_h2[(size_t)NN_ * 128];
__device__ float  g_sum[256], g_sq[256];
__device__ float  g_scale[256], g_shift[256];
__device__ float  g_pool[NG_ * 128];
__device__ int    g_count[NG_];

// bf16 helpers: arrays of ushort bf16, accessed pairwise via uint
__device__ __forceinline__ float bflo(unsigned int q) { return __uint_as_float(q << 16); }
__device__ __forceinline__ float bfhi(unsigned int q) { return __uint_as_float(q & 0xFFFF0000u); }
__device__ __forceinline__ unsigned int f2bf(float f) {
    unsigned int u = __float_as_uint(f);
    return (u + 0x7FFFu + ((u >> 16) & 1u)) >> 16;
}
__device__ __forceinline__ unsigned int pack2(float a, float b) {
    return f2bf(a) | (f2bf(b) << 16);
}

// ---------------- init ----------------
__global__ void k_zero() {
    int i = blockIdx.x * blockDim.x + threadIdx.x;
    int stride = gridDim.x * blockDim.x;
    for (int j = i; j < NN_; j += stride) g_deg[j] = 0;
    for (int j = i; j < 256; j += stride) { g_sum[j] = 0.f; g_sq[j] = 0.f; }
}

// ---------------- CSR build ----------------
__global__ void k_hist(const int* __restrict__ dst) {
    int e = blockIdx.x * blockDim.x + threadIdx.x;
    if (e < NE_) atomicAdd(&g_deg[dst[e]], 1);
}

__global__ void k_scan1() {
    __shared__ int sd[256];
    int b = blockIdx.x, t = threadIdx.x, i = b * 256 + t;
    int v = (i < NN_) ? g_deg[i] : 0;
    sd[t] = v;
    __syncthreads();
    for (int off = 1; off < 256; off <<= 1) {
        int tv = (t >= off) ? sd[t - off] : 0;
        __syncthreads();
        sd[t] += tv;
        __syncthreads();
    }
    if (i < NN_) g_rowstart[i] = sd[t] - v;   // block-local exclusive
    if (t == 255) g_bsum[b] = sd[255];
}

__global__ void k_scan2() {
    __shared__ int sd[256];
    int t = threadIdx.x;
    int v = (t < NBLK_SCAN) ? g_bsum[t] : 0;
    sd[t] = v;
    __syncthreads();
    for (int off = 1; off < 256; off <<= 1) {
        int tv = (t >= off) ? sd[t - off] : 0;
        __syncthreads();
        sd[t] += tv;
        __syncthreads();
    }
    if (t < NBLK_SCAN) g_boff[t] = sd[t] - v;
    if (t == 255) g_rowstart[NN_] = sd[255];
}

__global__ void k_scan3() {
    int i = blockIdx.x * blockDim.x + threadIdx.x;
    if (i < NN_) {
        int r = g_rowstart[i] + g_boff[i >> 8];
        g_rowstart[i] = r;
        g_cursor[i] = r;
    }
}

__global__ void k_scatter(const int* __restrict__ src, const int* __restrict__ dst,
                          const float* __restrict__ ea) {
    int e = blockIdx.x * blockDim.x + threadIdx.x;
    if (e < NE_) {
        int pos = atomicAdd(&g_cursor[dst[e]], 1);
        g_srccsr[pos] = src[e];
        g_eacsr[pos] = reinterpret_cast<const float4*>(ea)[e];
    }
}

// ---------------- layer-1 node transforms: xl1/xr1 = x@W + b (bf16 out) ----------
__global__ void k_xform1(const float* __restrict__ x,
                         const float* __restrict__ Wl, const float* __restrict__ bl,
                         const float* __restrict__ Wr, const float* __restrict__ br) {
    int n = blockIdx.x * 4 + (threadIdx.x >> 6);
    int lane = threadIdx.x & 63;
    if (n >= NN_) return;
    float x0 = x[2 * n], x1 = x[2 * n + 1];
    int c4 = lane * 4;
    float l0 = x0 * Wl[c4 + 0] + x1 * Wl[256 + c4 + 0] + bl[c4 + 0];
    float l1 = x0 * Wl[c4 + 1] + x1 * Wl[256 + c4 + 1] + bl[c4 + 1];
    float l2 = x0 * Wl[c4 + 2] + x1 * Wl[256 + c4 + 2] + bl[c4 + 2];
    float l3 = x0 * Wl[c4 + 3] + x1 * Wl[256 + c4 + 3] + bl[c4 + 3];
    float r0 = x0 * Wr[c4 + 0] + x1 * Wr[256 + c4 + 0] + br[c4 + 0];
    float r1 = x0 * Wr[c4 + 1] + x1 * Wr[256 + c4 + 1] + br[c4 + 1];
    float r2 = x0 * Wr[c4 + 2] + x1 * Wr[256 + c4 + 2] + br[c4 + 2];
    float r3 = x0 * Wr[c4 + 3] + x1 * Wr[256 + c4 + 3] + br[c4 + 3];
    *reinterpret_cast<uint2*>(g_xl1 + (size_t)n * 256 + c4) = make_uint2(pack2(l0, l1), pack2(l2, l3));
    *reinterpret_cast<uint2*>(g_xr1 + (size_t)n * 256 + c4) = make_uint2(pack2(r0, r1), pack2(r2, r3));
}

// ---------------- fused GATv2 layer: flash-style, wave per node ----------------
template <int LAYER>
__global__ void k_gat(const float* __restrict__ att, const float* __restrict__ We,
                      const float* __restrict__ bias) {
    constexpr int C = (LAYER == 1) ? 64 : 128;    // channels per head
    constexpr int GL = C / 4;                     // lanes per head group
    const ushort_t* __restrict__ xl = (LAYER == 1) ? g_xl1 : g_xl2;
    const ushort_t* __restrict__ xr = (LAYER == 1) ? g_xr1 : g_xr2;
    float* __restrict__ hout = (LAYER == 1) ? g_h1 : g_h2;

    int wv = threadIdx.x >> 6, lane = threadIdx.x & 63;
    int n = blockIdx.x * 4 + wv;
    if (n >= NN_) return;
    int c4 = lane * 4;

    float a0 = att[c4], a1 = att[c4 + 1], a2c = att[c4 + 2], a3 = att[c4 + 3];
    float we00 = We[c4], we01 = We[c4 + 1], we02 = We[c4 + 2], we03 = We[c4 + 3];
    float we10 = We[256 + c4], we11 = We[256 + c4 + 1], we12 = We[256 + c4 + 2], we13 = We[256 + c4 + 3];
    float we20 = We[512 + c4], we21 = We[512 + c4 + 1], we22 = We[512 + c4 + 2], we23 = We[512 + c4 + 3];
    float we30 = We[768 + c4], we31 = We[768 + c4 + 1], we32 = We[768 + c4 + 2], we33 = We[768 + c4 + 3];
    uint2 xq = *reinterpret_cast<const uint2*>(xr + (size_t)n * 256 + c4);
    float xr0 = bflo(xq.x), xr1 = bfhi(xq.x), xr2 = bflo(xq.y), xr3 = bfhi(xq.y);

    int s0 = g_rowstart[n];
    int d = g_rowstart[n + 1] - s0;

    float mrun = -INFINITY, den = 0.f;
    float acc0 = 0.f, acc1 = 0.f, acc2 = 0.f, acc3 = 0.f;

    int   sA = 0;
    float4 eaA = make_float4(0.f, 0.f, 0.f, 0.f);
    uint2 rowA = make_uint2(0u, 0u);
    if (d > 0) {
        sA = g_srccsr[s0];
        eaA = g_eacsr[s0];
        rowA = *reinterpret_cast<const uint2*>(xl + (size_t)sA * 256 + c4);
    }
    for (int i = 0; i < d; ++i) {
        int   sB = sA;
        float4 eaB = eaA;
        uint2 rowB = rowA;
        if (i + 1 < d) {
            sB = g_srccsr[s0 + i + 1];
            eaB = g_eacsr[s0 + i + 1];
            rowB = *reinterpret_cast<const uint2*>(xl + (size_t)sB * 256 + c4);
        }
        float xl0 = bflo(rowA.x), xl1 = bfhi(rowA.x), xl2 = bflo(rowA.y), xl3 = bfhi(rowA.y);
        float z0 = xl0 + xr0 + eaA.x * we00 + eaA.y * we10 + eaA.z * we20 + eaA.w * we30;
        float z1 = xl1 + xr1 + eaA.x * we01 + eaA.y * we11 + eaA.z * we21 + eaA.w * we31;
        float z2 = xl2 + xr2 + eaA.x * we02 + eaA.y * we12 + eaA.z * we22 + eaA.w * we32;
        float z3 = xl3 + xr3 + eaA.x * we03 + eaA.y * we13 + eaA.z * we23 + eaA.w * we33;
        z0 = fmaxf(z0, 0.2f * z0); z1 = fmaxf(z1, 0.2f * z1);
        z2 = fmaxf(z2, 0.2f * z2); z3 = fmaxf(z3, 0.2f * z3);
        float t = z0 * a0 + z1 * a1 + z2 * a2c + z3 * a3;
#pragma unroll
        for (int off = 1; off < GL; off <<= 1) t += __shfl_xor(t, off);
        float mnew = fmaxf(mrun, t);
        float scl = __expf(mrun - mnew);
        float w = __expf(t - mnew);
        den = den * scl + w;
        acc0 = acc0 * scl + w * xl0;
        acc1 = acc1 * scl + w * xl1;
        acc2 = acc2 * scl + w * xl2;
        acc3 = acc3 * scl + w * xl3;
        mrun = mnew;
        sA = sB; eaA = eaB; rowA = rowB;
    }
    float inv = 1.f / (den + 1e-16f);
    if (LAYER == 1) {
        float4 o = make_float4(acc0 * inv + bias[c4 + 0], acc1 * inv + bias[c4 + 1],
                               acc2 * inv + bias[c4 + 2], acc3 * inv + bias[c4 + 3]);
        *reinterpret_cast<float4*>(hout + (size_t)n * 256 + c4) = o;
    } else {
        float v0 = acc0 * inv, v1 = acc1 * inv, v2 = acc2 * inv, v3 = acc3 * inv;
        float u0 = __shfl_xor(v0, 32), u1 = __shfl_xor(v1, 32);
        float u2 = __shfl_xor(v2, 32), u3 = __shfl_xor(v3, 32);
        if (lane < 32) {
            float4 o = make_float4(0.5f * (v0 + u0) + bias[c4 + 0],
                                   0.5f * (v1 + u1) + bias[c4 + 1],
                                   0.5f * (v2 + u2) + bias[c4 + 2],
                                   0.5f * (v3 + u3) + bias[c4 + 3]);
            *reinterpret_cast<float4*>(hout + (size_t)n * 128 + c4) = o;
        }
    }
}

// ---------------- batchnorm ----------------
template <int C>
__global__ void k_bn_stats() {
    const float* h = (C == 256) ? (const float*)g_h1 : (const float*)g_h2;
    int c = threadIdx.x;
    int r0 = blockIdx.x * 100;
    float s = 0.f, ss = 0.f;
    for (int r = 0; r < 100; ++r) {
        float v = h[(size_t)(r0 + r) * C + c];
        s += v; ss += v * v;
    }
    atomicAdd(&g_sum[c], s);
    atomicAdd(&g_sq[c], ss);
}

template <int C>
__global__ void k_bn_finalize(const float* __restrict__ g, const float* __restrict__ b) {
    int c = threadIdx.x;
    float mu = g_sum[c] / (float)NN_;
    float var = g_sq[c] / (float)NN_ - mu * mu;
    float sc = g[c] * rsqrtf(var + 1e-5f);
    g_scale[c] = sc;
    g_shift[c] = b[c] - mu * sc;
    g_sum[c] = 0.f; g_sq[c] = 0.f;
}

// BN+ELU for layer1, emitting bf16 g_h1b (feeds MFMA GEMM); vectorized 8-wide
__global__ void k_bn_apply1() {
    int i = blockIdx.x * blockDim.x + threadIdx.x;
    int stride = gridDim.x * blockDim.x;
    for (int j8 = i; j8 < NN_ * 32; j8 += stride) {
        size_t base = (size_t)j8 * 8;
        int c0 = (int)(base & 255);
        float4 v0 = *reinterpret_cast<const float4*>(g_h1 + base);
        float4 v1 = *reinterpret_cast<const float4*>(g_h1 + base + 4);
        float e[8];
        e[0] = v0.x * g_scale[c0 + 0] + g_shift[c0 + 0];
        e[1] = v0.y * g_scale[c0 + 1] + g_shift[c0 + 1];
        e[2] = v0.z * g_scale[c0 + 2] + g_shift[c0 + 2];
        e[3] = v0.w * g_scale[c0 + 3] + g_shift[c0 + 3];
        e[4] = v1.x * g_scale[c0 + 4] + g_shift[c0 + 4];
        e[5] = v1.y * g_scale[c0 + 5] + g_shift[c0 + 5];
        e[6] = v1.z * g_scale[c0 + 6] + g_shift[c0 + 6];
        e[7] = v1.w * g_scale[c0 + 7] + g_shift[c0 + 7];
#pragma unroll
        for (int q = 0; q < 8; ++q) e[q] = e[q] > 0.f ? e[q] : expm1f(e[q]);
        uint4 o = make_uint4(pack2(e[0], e[1]), pack2(e[2], e[3]),
                             pack2(e[4], e[5]), pack2(e[6], e[7]));
        *reinterpret_cast<uint4*>(g_h1b + base) = o;
    }
}

// BN+ELU for layer2 output h2 (fp32 in place)
__global__ void k_bn_apply2() {
    int i = blockIdx.x * blockDim.x + threadIdx.x;
    int stride = gridDim.x * blockDim.x;
    for (int j = i; j < NN_ * 128; j += stride) {
        int c = j & 127;
        float v = g_h2[j] * g_scale[c] + g_shift[c];
        g_h2[j] = v > 0.f ? v : expm1f(v);
    }
}

// ---------------- weight convert+transpose: W[k][n] fp32 -> Wt[n][k] bf16 --------
__global__ void k_wconv(const float* __restrict__ Wl, const float* __restrict__ Wr) {
    int n = blockIdx.x, k = threadIdx.x;   // 256 x 256
    g_wl2t[n * 256 + k] = (ushort_t)f2bf(Wl[(size_t)k * 256 + n]);
    g_wr2t[n * 256 + k] = (ushort_t)f2bf(Wr[(size_t)k * 256 + n]);
}

// ---------------- MFMA dual GEMM: h1b(40000x256,bf16) @ {Wl2,Wr2} -> xl2/xr2 ----
// Block: 256 thr (4 waves). Tile: BM=128 (wave owns 32 rows), BN=64, both matrices.
// mfma_f32_16x16x32_bf16; A frag: row=lane&15, k=(lane>>4)*8+j; C/D: col=lane&15,
// row=(lane>>4)*4+reg (m89/m91-verified). LDS rows padded to 40 ushort.
// Staging uses uint4 (16B = 8 bf16) -- r8 bug was uint2 (4 bf16) leaving half
// of each segment uninitialized -> NaN garbage into MFMA.
__global__ __launch_bounds__(256) void k_gemm2(const float* __restrict__ bl,
                                               const float* __restrict__ br) {
    __shared__ ushort_t As[128][40];
    __shared__ ushort_t Bs[2][64][40];
    int tid = threadIdx.x;
    int w = tid >> 6, lane = tid & 63;
    int m0 = blockIdx.x * 128, n0 = blockIdx.y * 64;

    f32x4 acc[2][4][2] = {};

    for (int k0 = 0; k0 < 256; k0 += 32) {
        // stage A: 128 rows x 32 bf16 = 512 chunks of 8 bf16 (16B each)
#pragma unroll
        for (int c = tid; c < 512; c += 256) {
            int row = c >> 2, seg = c & 3;
            int gr = m0 + row; gr = gr < NN_ ? gr : NN_ - 1;
            uint4 v = *reinterpret_cast<const uint4*>(g_h1b + (size_t)gr * 256 + k0 + seg * 8);
            *reinterpret_cast<uint4*>(&As[row][seg * 8]) = v;
        }
        // stage B (both matrices): 64 rows x 32 bf16 each
        {
            int row = tid >> 2, seg = tid & 3;
            uint4 v0 = *reinterpret_cast<const uint4*>(g_wl2t + (size_t)(n0 + row) * 256 + k0 + seg * 8);
            *reinterpret_cast<uint4*>(&Bs[0][row][seg * 8]) = v0;
            uint4 v1 = *reinterpret_cast<const uint4*>(g_wr2t + (size_t)(n0 + row) * 256 + k0 + seg * 8);
            *reinterpret_cast<uint4*>(&Bs[1][row][seg * 8]) = v1;
        }
        __syncthreads();
        int kb = (lane >> 4) * 8;
        bf16x8 a0 = *reinterpret_cast<const bf16x8*>(&As[w * 32 + (lane & 15)][kb]);
        bf16x8 a1 = *reinterpret_cast<const bf16x8*>(&As[w * 32 + 16 + (lane & 15)][kb]);
        bf16x8 b[4][2];
#pragma unroll
        for (int ni = 0; ni < 4; ++ni) {
            b[ni][0] = *reinterpret_cast<const bf16x8*>(&Bs[0][ni * 16 + (lane & 15)][kb]);
            b[ni][1] = *reinterpret_cast<const bf16x8*>(&Bs[1][ni * 16 + (lane & 15)][kb]);
        }
#pragma unroll
        for (int ni = 0; ni < 4; ++ni) {
#pragma unroll
            for (int mat = 0; mat < 2; ++mat) {
                acc[0][ni][mat] = __builtin_amdgcn_mfma_f32_16x16x32_bf16(a0, b[ni][mat], acc[0][ni][mat], 0, 0, 0);
                acc[1][ni][mat] = __builtin_amdgcn_mfma_f32_16x16x32_bf16(a1, b[ni][mat], acc[1][ni][mat], 0, 0, 0);
            }
        }
        __syncthreads();
    }
    // epilogue: add bias, store bf16
#pragma unroll
    for (int mat = 0; mat < 2; ++mat) {
        const float* bb = mat ? br : bl;
        ushort_t* outp = mat ? g_xr2 : g_xl2;
#pragma unroll
        for (int ni = 0; ni < 4; ++ni) {
            int gcol = n0 + ni * 16 + (lane & 15);
            float bv = bb[gcol];
#pragma unroll
            for (int mi = 0; mi < 2; ++mi) {
#pragma unroll
                for (int r = 0; r < 4; ++r) {
                    int grow = m0 + w * 32 + mi * 16 + (lane >> 4) * 4 + r;
                    if (grow < NN_)
                        outp[(size_t)grow * 256 + gcol] = (ushort_t)f2bf(acc[mi][ni][mat][r] + bv);
                }
            }
        }
    }
}

// ---------------- global mean pool (batch is sorted -> block per graph) ----------
__global__ void k_pool2(const int* __restrict__ batch) {
    int g = blockIdx.x, t = threadIdx.x;  // 128 threads
    __shared__ int sbeg, send;
    if (t == 0) {
        int lo = 0, hi = NN_;
        while (lo < hi) { int mid = (lo + hi) >> 1; if (batch[mid] < g) lo = mid + 1; else hi = mid; }
        sbeg = lo;
    }
    if (t == 1) {
        int lo = 0, hi = NN_;
        while (lo < hi) { int mid = (lo + hi) >> 1; if (batch[mid] <= g) lo = mid + 1; else hi = mid; }
        send = lo;
    }
    __syncthreads();
    int beg = sbeg, end = send;
    float acc = 0.f;
    for (int n = beg; n < end; ++n) acc += g_h2[(size_t)n * 128 + t];
    g_pool[g * 128 + t] = acc;
    if (t == 0) g_count[g] = end - beg;
}

// ---------------- MLP head ----------------
__global__ void k_head(const float* __restrict__ W1, const float* __restrict__ b1,
                       const float* __restrict__ W2, const float* __restrict__ b2,
                       float* __restrict__ out) {
    int g = blockIdx.x, t = threadIdx.x;  // 64 threads
    __shared__ float p[128], hm[64];
    float cnt = fmaxf((float)g_count[g], 1.f);
    float inv = 1.f / cnt;
    p[t] = g_pool[g * 128 + t] * inv;
    p[t + 64] = g_pool[g * 128 + 64 + t] * inv;
    __syncthreads();
    float a = b1[t];
    for (int k = 0; k < 128; ++k) a += p[k] * W1[k * 64 + t];
    hm[t] = a > 0.f ? a : expm1f(a);
    __syncthreads();
    if (t < 12) {
        float o = b2[t];
        for (int k = 0; k < 64; ++k) o += hm[k] * W2[k * 12 + t];
        out[g * 12 + t] = o;
    }
}

// ---------------- launch ----------------
extern "C" void kernel_launch(void* const* d_in, const int* in_sizes, int n_in,
                              void* d_out, int out_size, void* d_ws, size_t ws_size,
                              hipStream_t stream) {
    const float* x     = (const float*)d_in[0];
    const int*   ei    = (const int*)d_in[1];
    const float* ea    = (const float*)d_in[2];
    const int*   batch = (const int*)d_in[3];
    const float* Wl1   = (const float*)d_in[4];
    const float* bl1   = (const float*)d_in[5];
    const float* Wr1   = (const float*)d_in[6];
    const float* br1   = (const float*)d_in[7];
    const float* We1   = (const float*)d_in[8];
    const float* att1  = (const float*)d_in[9];
    const float* bias1 = (const float*)d_in[10];
    const float* g1    = (const float*)d_in[11];
    const float* be1   = (const float*)d_in[12];
    const float* Wl2   = (const float*)d_in[13];
    const float* bl2   = (const float*)d_in[14];
    const float* Wr2   = (const float*)d_in[15];
    const float* br2   = (const float*)d_in[16];
    const float* We2   = (const float*)d_in[17];
    const float* att2  = (const float*)d_in[18];
    const float* bias2 = (const float*)d_in[19];
    const float* g2    = (const float*)d_in[20];
    const float* be2   = (const float*)d_in[21];
    const float* Wlin1 = (const float*)d_in[22];
    const float* blin1 = (const float*)d_in[23];
    const float* Wlin2 = (const float*)d_in[24];
    const float* blin2 = (const float*)d_in[25];
    float* out = (float*)d_out;
    const int* src = ei;
    const int* dst = ei + NE_;

    k_zero<<<256, 256, 0, stream>>>();
    k_hist<<<2500, 256, 0, stream>>>(dst);
    k_scan1<<<NBLK_SCAN, 256, 0, stream>>>();
    k_scan2<<<1, 256, 0, stream>>>();
    k_scan3<<<NBLK_SCAN, 256, 0, stream>>>();
    k_scatter<<<2500, 256, 0, stream>>>(src, dst, ea);

    // layer 1
    k_xform1<<<10000, 256, 0, stream>>>(x, Wl1, bl1, Wr1, br1);
    k_wconv<<<256, 256, 0, stream>>>(Wl2, Wr2);    // independent; early
    k_gat<1><<<10000, 256, 0, stream>>>(att1, We1, bias1);
    k_bn_stats<256><<<400, 256, 0, stream>>>();
    k_bn_finalize<256><<<1, 256, 0, stream>>>(g1, be1);
    k_bn_apply1<<<2048, 256, 0, stream>>>();

    // layer 2 projections: MFMA bf16 dual-GEMM
    k_gemm2<<<dim3(313, 4), 256, 0, stream>>>(bl2, br2);

    // layer 2
    k_gat<2><<<10000, 256, 0, stream>>>(att2, We2, bias2);
    k_bn_stats<128><<<400, 128, 0, stream>>>();
    k_bn_finalize<128><<<1, 128, 0, stream>>>(g2, be2);
    k_bn_apply2<<<2048, 256, 0, stream>>>();

    // pool + head
    k_pool2<<<NG_, 128, 0, stream>>>(batch);
    k_head<<<NG_, 64, 0, stream>>>(Wlin1, blin1, Wlin2, blin2, out);
}